// Round 1
// baseline (373.564 us; speedup 1.0000x reference)
//
#include <hip/hip_runtime.h>

#define T_TOK 4096
#define DIM   1024
#define FFD   2048
#define NEXP  4
#define NRP   8704      // 68*128 padded row capacity (worst-case padded total <= 8576)
#define MTILES 68

typedef unsigned short u16;
typedef __attribute__((ext_vector_type(8))) short short8;
typedef __attribute__((ext_vector_type(4))) float f32x4;
typedef __attribute__((ext_vector_type(8))) unsigned short u16x8;
typedef __attribute__((ext_vector_type(4))) unsigned short u16x4;

typedef __attribute__((address_space(1))) unsigned int as1_u32;
typedef __attribute__((address_space(3))) unsigned int as3_u32;

__device__ __forceinline__ u16 f2bf(float f) {
  union { float f; unsigned u; } v; v.f = f;
  unsigned u = v.u;
  return (u16)((u + 0x7fffu + ((u >> 16) & 1u)) >> 16);   // RNE
}
__device__ __forceinline__ float bf2f(u16 h) {
  union { unsigned u; float f; } v; v.u = ((unsigned)h) << 16;
  return v.f;
}
__device__ __forceinline__ void gload16(const void* g, void* l) {
  __builtin_amdgcn_global_load_lds((const as1_u32*)g, (as3_u32*)l, 16, 0, 0);
}

// ---------------- router: fp32 logits, softmax top-2, renorm ----------------
__global__ void router_k(const float* __restrict__ x, const float* __restrict__ gw,
                         float* __restrict__ logits_out, int* __restrict__ sel,
                         float* __restrict__ selw) {
  int t = blockIdx.x;
  int lane = threadIdx.x;           // block = 64 (one wave)
  float xv[16];
#pragma unroll
  for (int i = 0; i < 16; ++i) xv[i] = x[(size_t)t * DIM + lane + i * 64];
  float l[4];
#pragma unroll
  for (int e = 0; e < 4; ++e) {
    float s = 0.f;
#pragma unroll
    for (int i = 0; i < 16; ++i) s += xv[i] * gw[e * DIM + lane + i * 64];
#pragma unroll
    for (int off = 32; off > 0; off >>= 1) s += __shfl_xor(s, off, 64);
    l[e] = s;
  }
  if (lane == 0) {
#pragma unroll
    for (int e = 0; e < 4; ++e) logits_out[(size_t)t * 4 + e] = l[e];
    int e0 = 0; float b0 = l[0];
    for (int e = 1; e < 4; ++e) if (l[e] > b0) { b0 = l[e]; e0 = e; }
    int e1 = -1; float b1 = -3.4e38f;
    for (int e = 0; e < 4; ++e) if (e != e0 && l[e] > b1) { b1 = l[e]; e1 = e; }
    // renormalized top-2 softmax weights == exp ratio
    float p1 = expf(b1 - b0);
    float w0 = 1.f / (1.f + p1);
    sel[2 * t] = e0; sel[2 * t + 1] = e1;
    selw[2 * t] = w0; selw[2 * t + 1] = 1.f - w0;
  }
}

// ------------- deterministic bucket assignment (single block) ---------------
__global__ void scan_k(const int* __restrict__ sel, int* __restrict__ pos,
                       int* __restrict__ offs, int* __restrict__ rowtok,
                       int* __restrict__ pairrow) {
  __shared__ int base[4];
  __shared__ int wsum[16];
  __shared__ int off_s[5];
  int tid = threadIdx.x, lane = tid & 63, wid = tid >> 6;   // 1024 threads = 16 waves
  if (tid < 4) base[tid] = 0;
  __syncthreads();
  for (int chunk = 0; chunk < 4; ++chunk) {
    int t = chunk * 1024 + tid;
    int e0 = sel[2 * t], e1 = sel[2 * t + 1];
    for (int e = 0; e < 4; ++e) {
      bool f = (e0 == e) || (e1 == e);
      unsigned long long m = __ballot(f);
      int within = __popcll(m & ((1ull << lane) - 1ull));
      if (lane == 0) wsum[wid] = __popcll(m);
      __syncthreads();
      int wbase = 0, tot = 0;
      for (int i = 0; i < 16; ++i) { int v = wsum[i]; if (i < wid) wbase += v; tot += v; }
      if (f) {
        int p = base[e] + wbase + within;
        if (e0 == e) pos[2 * t] = p; else pos[2 * t + 1] = p;
      }
      __syncthreads();
      if (tid == 0) base[e] += tot;
      __syncthreads();
    }
  }
  if (tid == 0) {
    int o = 0;
    for (int e = 0; e < 4; ++e) { off_s[e] = o; o += ((base[e] + 127) >> 7) << 7; }
    off_s[4] = o;
    for (int i = 0; i < 5; ++i) offs[i] = off_s[i];
  }
  __syncthreads();
  for (int r = tid; r < NRP; r += 1024) rowtok[r] = -1;
  __syncthreads();
  for (int t = tid; t < T_TOK; t += 1024) {
#pragma unroll
    for (int s = 0; s < 2; ++s) {
      int e = sel[2 * t + s];
      int rr = off_s[e] + pos[2 * t + s];
      pairrow[2 * t + s] = rr;
      rowtok[rr] = t;
    }
  }
}

// ---------------- gather x rows (bucket order) -> bf16 ----------------------
__global__ void gather_k(const float* __restrict__ x, const int* __restrict__ rowtok,
                         u16* __restrict__ xg) {
  int r = blockIdx.x, tid = threadIdx.x;   // 256 threads, 4 floats each
  int t = rowtok[r];
  float4 v = make_float4(0.f, 0.f, 0.f, 0.f);
  if (t >= 0) v = ((const float4*)(x + (size_t)t * DIM))[tid];
  u16x4 o;
  o[0] = f2bf(v.x); o[1] = f2bf(v.y); o[2] = f2bf(v.z); o[3] = f2bf(v.w);
  ((u16x4*)(xg + (size_t)r * DIM))[tid] = o;
}

// ---------------- per-row LoRA A-projections (R=16) --------------------------
__global__ void xa_k(const u16* __restrict__ xg, const float* __restrict__ Ag,
                     const float* __restrict__ Au, const int* __restrict__ offs,
                     float* __restrict__ xag, float* __restrict__ xau) {
  int r = blockIdx.x, lane = threadIdx.x;   // block = 64
  int e = 0;
  if (r >= offs[1]) e = 1;
  if (r >= offs[2]) e = 2;
  if (r >= offs[3]) e = 3;
  float xv[16];
#pragma unroll
  for (int i = 0; i < 16; ++i) xv[i] = bf2f(xg[(size_t)r * DIM + lane + i * 64]);
  for (int q = 0; q < 16; ++q) {
    const float* ag = Ag + ((size_t)e * 16 + q) * DIM;
    const float* au = Au + ((size_t)e * 16 + q) * DIM;
    float sg = 0.f, su = 0.f;
#pragma unroll
    for (int i = 0; i < 16; ++i) { sg += xv[i] * ag[lane + i * 64]; su += xv[i] * au[lane + i * 64]; }
#pragma unroll
    for (int off = 32; off > 0; off >>= 1) { sg += __shfl_xor(sg, off, 64); su += __shfl_xor(su, off, 64); }
    if (lane == 0) { xag[(size_t)r * 16 + q] = sg; xau[(size_t)r * 16 + q] = su; }
  }
}

__global__ void aad_k(const u16* __restrict__ act, const float* __restrict__ Ad,
                      const int* __restrict__ offs, float* __restrict__ aad) {
  int r = blockIdx.x, lane = threadIdx.x;
  int e = 0;
  if (r >= offs[1]) e = 1;
  if (r >= offs[2]) e = 2;
  if (r >= offs[3]) e = 3;
  float xv[32];
#pragma unroll
  for (int i = 0; i < 32; ++i) xv[i] = bf2f(act[(size_t)r * FFD + lane + i * 64]);
  for (int q = 0; q < 16; ++q) {
    const float* a = Ad + ((size_t)e * 16 + q) * FFD;
    float s = 0.f;
#pragma unroll
    for (int i = 0; i < 32; ++i) s += xv[i] * a[lane + i * 64];
#pragma unroll
    for (int off = 32; off > 0; off >>= 1) s += __shfl_xor(s, off, 64);
    if (lane == 0) aad[(size_t)r * 16 + q] = s;
  }
}

// ---------------- weight transpose fp32[K][N] -> bf16[N][K] ------------------
__global__ void transpose_k(const float* __restrict__ in, u16* __restrict__ out,
                            int K, int N) {
  int e = blockIdx.z;
  int n0 = blockIdx.x * 32, k0 = blockIdx.y * 32;
  const float* I = in + (size_t)e * K * N;
  u16* O = out + (size_t)e * N * K;
  __shared__ u16 tile[32][33];
#pragma unroll
  for (int i = 0; i < 4; ++i) {
    int k = k0 + threadIdx.y + i * 8;
    tile[threadIdx.y + i * 8][threadIdx.x] = f2bf(I[(size_t)k * N + n0 + threadIdx.x]);
  }
  __syncthreads();
#pragma unroll
  for (int i = 0; i < 4; ++i) {
    int n = n0 + threadIdx.y + i * 8;
    O[(size_t)n * K + k0 + threadIdx.x] = tile[threadIdx.x][threadIdx.y + i * 8];
  }
}

// ---------------- GEMM1: act = swiglu(x@Wgu + b + lora) ---------------------
// tile 128 rows x (64 gate cols | 64 up cols), BK=32, 4 waves (4x1: wave w owns rows w*32..+31)
__global__ __launch_bounds__(256) void gemm1_k(
    const u16* __restrict__ xg, const u16* __restrict__ wgu_t,
    const float* __restrict__ gub, const float* __restrict__ Bg,
    const float* __restrict__ Bu, const float* __restrict__ xag,
    const float* __restrict__ xau, const int* __restrict__ offs,
    u16* __restrict__ act) {
  __shared__ __align__(16) u16 sAB[8192];
  u16* sA = sAB;          // [128][32]
  u16* sB = sAB + 4096;   // [128][32]  (rows 0..63 gate, 64..127 up)
  int tid = threadIdx.x, w = tid >> 6, lane = tid & 63;
  int f0 = blockIdx.x * 64;
  int row0 = blockIdx.y * 128;
  int e = 0;
  if (row0 >= offs[1]) e = 1;
  if (row0 >= offs[2]) e = 2;
  if (row0 >= offs[3]) e = 3;

  int srow = w * 32 + (lane >> 2);
  int scol = (lane & 3) * 8;
  const u16* gA = xg + (size_t)(row0 + srow) * DIM + scol;
  int n1 = srow, n2 = srow + 16;
  int gr1 = (n1 < 64) ? (f0 + n1) : (2048 + f0 + n1 - 64);
  int gr2 = (n2 < 64) ? (f0 + n2) : (2048 + f0 + n2 - 64);
  const u16* gB1 = wgu_t + ((size_t)e << 22) + (size_t)gr1 * DIM + scol;
  const u16* gB2 = wgu_t + ((size_t)e << 22) + (size_t)gr2 * DIM + scol;
  u16* lA = sA + w * 1024;
  u16* lB = sB + w * 1024;

  f32x4 acc[2][8];
#pragma unroll
  for (int i = 0; i < 2; ++i)
#pragma unroll
    for (int j = 0; j < 8; ++j) acc[i][j] = f32x4{0.f, 0.f, 0.f, 0.f};

  for (int kk = 0; kk < DIM; kk += 32) {
    __syncthreads();
    gload16(gA + kk, lA);
    gload16(gA + 16 * DIM + kk, lA + 512);
    gload16(gB1 + kk, lB);
    gload16(gB2 + kk, lB + 512);
    __syncthreads();
    short8 a[2], b[8];
#pragma unroll
    for (int mi = 0; mi < 2; ++mi)
      a[mi] = *(const short8*)&sA[(w * 32 + mi * 16 + (lane & 15)) * 32 + (lane >> 4) * 8];
#pragma unroll
    for (int ni = 0; ni < 8; ++ni)
      b[ni] = *(const short8*)&sB[(ni * 16 + (lane & 15)) * 32 + (lane >> 4) * 8];
#pragma unroll
    for (int mi = 0; mi < 2; ++mi)
#pragma unroll
      for (int ni = 0; ni < 8; ++ni)
        acc[mi][ni] = __builtin_amdgcn_mfma_f32_16x16x32_bf16(a[mi], b[ni], acc[mi][ni], 0, 0, 0);
  }

  // ---- LoRA + bias as one extra K=32 MFMA step: k0..15 = 2*xa / B, k16 = 1 / bias ----
  __syncthreads();
  {
    int r = tid >> 1, kh = tid & 1;
    u16 tmp[16];
    if (kh == 0) {
#pragma unroll
      for (int q = 0; q < 16; ++q) tmp[q] = f2bf(2.f * xag[(size_t)(row0 + r) * 16 + q]);
    } else {
#pragma unroll
      for (int q = 0; q < 16; ++q) tmp[q] = 0;
      tmp[0] = 0x3f80;   // 1.0 at k=16
    }
    *(u16x8*)&sA[r * 32 + kh * 16] = *(u16x8*)&tmp[0];
    *(u16x8*)&sA[r * 32 + kh * 16 + 8] = *(u16x8*)&tmp[8];
    int f = (r < 64) ? (f0 + r) : (f0 + r - 64);
    const float* Bsrc = (r < 64) ? Bg : Bu;
    float bias = gub[e * 4096 + ((r < 64) ? f : (2048 + f))];
    if (kh == 0) {
#pragma unroll
      for (int q = 0; q < 16; ++q) tmp[q] = f2bf(Bsrc[((size_t)e * FFD + f) * 16 + q]);
    } else {
#pragma unroll
      for (int q = 0; q < 16; ++q) tmp[q] = 0;
      tmp[0] = f2bf(bias);
    }
    *(u16x8*)&sB[r * 32 + kh * 16] = *(u16x8*)&tmp[0];
    *(u16x8*)&sB[r * 32 + kh * 16 + 8] = *(u16x8*)&tmp[8];
  }
  __syncthreads();
  {  // gate half
    short8 a[2], b[4];
#pragma unroll
    for (int mi = 0; mi < 2; ++mi)
      a[mi] = *(const short8*)&sA[(w * 32 + mi * 16 + (lane & 15)) * 32 + (lane >> 4) * 8];
#pragma unroll
    for (int ni = 0; ni < 4; ++ni)
      b[ni] = *(const short8*)&sB[(ni * 16 + (lane & 15)) * 32 + (lane >> 4) * 8];
#pragma unroll
    for (int mi = 0; mi < 2; ++mi)
#pragma unroll
      for (int ni = 0; ni < 4; ++ni)
        acc[mi][ni] = __builtin_amdgcn_mfma_f32_16x16x32_bf16(a[mi], b[ni], acc[mi][ni], 0, 0, 0);
  }
  __syncthreads();
  {  // swap A-lora to xa_up
    int r = tid >> 1, kh = tid & 1;
    u16 tmp[16];
    if (kh == 0) {
#pragma unroll
      for (int q = 0; q < 16; ++q) tmp[q] = f2bf(2.f * xau[(size_t)(row0 + r) * 16 + q]);
    } else {
#pragma unroll
      for (int q = 0; q < 16; ++q) tmp[q] = 0;
      tmp[0] = 0x3f80;
    }
    *(u16x8*)&sA[r * 32 + kh * 16] = *(u16x8*)&tmp[0];
    *(u16x8*)&sA[r * 32 + kh * 16 + 8] = *(u16x8*)&tmp[8];
  }
  __syncthreads();
  {  // up half
    short8 a[2], b[4];
#pragma unroll
    for (int mi = 0; mi < 2; ++mi)
      a[mi] = *(const short8*)&sA[(w * 32 + mi * 16 + (lane & 15)) * 32 + (lane >> 4) * 8];
#pragma unroll
    for (int ni = 0; ni < 4; ++ni)
      b[ni] = *(const short8*)&sB[((ni + 4) * 16 + (lane & 15)) * 32 + (lane >> 4) * 8];
#pragma unroll
    for (int mi = 0; mi < 2; ++mi)
#pragma unroll
      for (int ni = 0; ni < 4; ++ni)
        acc[mi][ni + 4] = __builtin_amdgcn_mfma_f32_16x16x32_bf16(a[mi], b[ni], acc[mi][ni + 4], 0, 0, 0);
  }
  __syncthreads();
  // ---- register-local SwiGLU, repack through LDS for coalesced bf16 store ----
#pragma unroll
  for (int mi = 0; mi < 2; ++mi)
#pragma unroll
    for (int ni = 0; ni < 4; ++ni)
#pragma unroll
      for (int j = 0; j < 4; ++j) {
        int lr = w * 32 + mi * 16 + (lane >> 4) * 4 + j;
        int lc = ni * 16 + (lane & 15);
        float g = acc[mi][ni][j];
        float u = acc[mi][ni + 4][j];
        float s = g / (1.f + __expf(-g));
        sAB[lr * 64 + lc] = f2bf(s * u);
      }
  __syncthreads();
#pragma unroll
  for (int it = 0; it < 4; ++it) {
    int idx = it * 256 + tid;
    int rr = idx >> 3, c8 = (idx & 7) * 8;
    *(u16x8*)(act + (size_t)(row0 + rr) * FFD + f0 + c8) = *(const u16x8*)&sAB[rr * 64 + c8];
  }
}

// ---------------- GEMM2: down = act@Wd + b + lora ----------------------------
__global__ __launch_bounds__(256) void gemm2_k(
    const u16* __restrict__ act, const u16* __restrict__ wd_t,
    const float* __restrict__ db, const float* __restrict__ Bd,
    const float* __restrict__ aad, const int* __restrict__ offs,
    float* __restrict__ down) {
  __shared__ __align__(16) u16 sAB[8192];
  u16* sA = sAB;
  u16* sB = sAB + 4096;
  int tid = threadIdx.x, w = tid >> 6, lane = tid & 63;
  int n0 = blockIdx.x * 128;
  int row0 = blockIdx.y * 128;
  int e = 0;
  if (row0 >= offs[1]) e = 1;
  if (row0 >= offs[2]) e = 2;
  if (row0 >= offs[3]) e = 3;
  int wm = w >> 1, wn = w & 1;

  int srow = w * 32 + (lane >> 2);
  int scol = (lane & 3) * 8;
  const u16* gA = act + (size_t)(row0 + srow) * FFD + scol;
  const u16* gB = wd_t + (size_t)e * DIM * FFD + (size_t)(n0 + srow) * FFD + scol;
  u16* lA = sA + w * 1024;
  u16* lB = sB + w * 1024;

  f32x4 acc[4][4];
#pragma unroll
  for (int i = 0; i < 4; ++i)
#pragma unroll
    for (int j = 0; j < 4; ++j) acc[i][j] = f32x4{0.f, 0.f, 0.f, 0.f};

  for (int kk = 0; kk < FFD; kk += 32) {
    __syncthreads();
    gload16(gA + kk, lA);
    gload16(gA + 16 * FFD + kk, lA + 512);
    gload16(gB + kk, lB);
    gload16(gB + 16 * FFD + kk, lB + 512);
    __syncthreads();
    short8 a[4], b[4];
#pragma unroll
    for (int mi = 0; mi < 4; ++mi)
      a[mi] = *(const short8*)&sA[(wm * 64 + mi * 16 + (lane & 15)) * 32 + (lane >> 4) * 8];
#pragma unroll
    for (int ni = 0; ni < 4; ++ni)
      b[ni] = *(const short8*)&sB[(wn * 64 + ni * 16 + (lane & 15)) * 32 + (lane >> 4) * 8];
#pragma unroll
    for (int mi = 0; mi < 4; ++mi)
#pragma unroll
      for (int ni = 0; ni < 4; ++ni)
        acc[mi][ni] = __builtin_amdgcn_mfma_f32_16x16x32_bf16(a[mi], b[ni], acc[mi][ni], 0, 0, 0);
  }

  // ---- LoRA-down + bias as one extra K=32 MFMA step ----
  __syncthreads();
  {
    int r = tid >> 1, kh = tid & 1;
    u16 tmp[16];
    if (kh == 0) {
#pragma unroll
      for (int q = 0; q < 16; ++q) tmp[q] = f2bf(2.f * aad[(size_t)(row0 + r) * 16 + q]);
    } else {
#pragma unroll
      for (int q = 0; q < 16; ++q) tmp[q] = 0;
      tmp[0] = 0x3f80;
    }
    *(u16x8*)&sA[r * 32 + kh * 16] = *(u16x8*)&tmp[0];
    *(u16x8*)&sA[r * 32 + kh * 16 + 8] = *(u16x8*)&tmp[8];
    if (kh == 0) {
#pragma unroll
      for (int q = 0; q < 16; ++q) tmp[q] = f2bf(Bd[((size_t)e * DIM + n0 + r) * 16 + q]);
    } else {
#pragma unroll
      for (int q = 0; q < 16; ++q) tmp[q] = 0;
      tmp[0] = f2bf(db[e * DIM + n0 + r]);
    }
    *(u16x8*)&sB[r * 32 + kh * 16] = *(u16x8*)&tmp[0];
    *(u16x8*)&sB[r * 32 + kh * 16 + 8] = *(u16x8*)&tmp[8];
  }
  __syncthreads();
  {
    short8 a[4], b[4];
#pragma unroll
    for (int mi = 0; mi < 4; ++mi)
      a[mi] = *(const short8*)&sA[(wm * 64 + mi * 16 + (lane & 15)) * 32 + (lane >> 4) * 8];
#pragma unroll
    for (int ni = 0; ni < 4; ++ni)
      b[ni] = *(const short8*)&sB[(wn * 64 + ni * 16 + (lane & 15)) * 32 + (lane >> 4) * 8];
#pragma unroll
    for (int mi = 0; mi < 4; ++mi)
#pragma unroll
      for (int ni = 0; ni < 4; ++ni)
        acc[mi][ni] = __builtin_amdgcn_mfma_f32_16x16x32_bf16(a[mi], b[ni], acc[mi][ni], 0, 0, 0);
  }
  // ---- store fp32 ----
#pragma unroll
  for (int mi = 0; mi < 4; ++mi)
#pragma unroll
    for (int ni = 0; ni < 4; ++ni)
#pragma unroll
      for (int j = 0; j < 4; ++j) {
        int lr = wm * 64 + mi * 16 + (lane >> 4) * 4 + j;
        int lc = wn * 64 + ni * 16 + (lane & 15);
        down[(size_t)(row0 + lr) * DIM + n0 + lc] = acc[mi][ni][j];
      }
}

// ---------------- weighted combine (full overwrite of final) -----------------
__global__ void combine_k(const float* __restrict__ down, const int* __restrict__ pairrow,
                          const float* __restrict__ selw, float* __restrict__ out) {
  int t = blockIdx.x, tid = threadIdx.x;   // 256 threads, one float4 each
  int r0 = pairrow[2 * t], r1 = pairrow[2 * t + 1];
  float w0 = selw[2 * t], w1 = selw[2 * t + 1];
  f32x4 a = *(const f32x4*)(down + (size_t)r0 * DIM + tid * 4);
  f32x4 b = *(const f32x4*)(down + (size_t)r1 * DIM + tid * 4);
  f32x4 o = a * w0 + b * w1;
  *(f32x4*)(out + (size_t)t * DIM + tid * 4) = o;
}

extern "C" void kernel_launch(void* const* d_in, const int* in_sizes, int n_in,
                              void* d_out, int out_size, void* d_ws, size_t ws_size,
                              hipStream_t stream) {
  const float* x         = (const float*)d_in[0];
  const float* gate_w    = (const float*)d_in[1];
  const float* gate_up_w = (const float*)d_in[2];
  const float* gate_up_b = (const float*)d_in[3];
  const float* down_w    = (const float*)d_in[4];
  const float* down_b    = (const float*)d_in[5];
  const float* A_gate    = (const float*)d_in[6];
  const float* B_gate    = (const float*)d_in[7];
  const float* A_up      = (const float*)d_in[8];
  const float* B_up      = (const float*)d_in[9];
  const float* A_down    = (const float*)d_in[10];
  const float* B_down    = (const float*)d_in[11];

  float* out_final  = (float*)d_out;
  float* out_logits = out_final + (size_t)T_TOK * DIM;

  char* ws = (char*)d_ws;
  size_t o = 0;
  auto take = [&](size_t bytes) -> void* {
    void* p = ws + o;
    o = (o + bytes + 255) & ~(size_t)255;
    return p;
  };
  int*   offs    = (int*)take(64);
  int*   sel     = (int*)take((size_t)T_TOK * 2 * 4);
  float* selw    = (float*)take((size_t)T_TOK * 2 * 4);
  int*   pos     = (int*)take((size_t)T_TOK * 2 * 4);
  int*   pairrow = (int*)take((size_t)T_TOK * 2 * 4);
  int*   rowtok  = (int*)take((size_t)NRP * 4);
  float* xa_g    = (float*)take((size_t)NRP * 16 * 4);
  float* xa_u    = (float*)take((size_t)NRP * 16 * 4);
  float* aad     = (float*)take((size_t)NRP * 16 * 4);
  u16*   xg      = (u16*)take((size_t)NRP * DIM * 2);
  u16*   actb    = (u16*)take((size_t)NRP * FFD * 2);
  float* downb   = (float*)take((size_t)NRP * DIM * 4);
  u16*   wgu_t   = (u16*)take((size_t)NEXP * 2 * FFD * DIM * 2);
  u16*   wd_t    = (u16*)take((size_t)NEXP * DIM * FFD * 2);
  (void)ws_size; (void)in_sizes; (void)n_in; (void)out_size;

  // weight transposes (fp32 [K][N] -> bf16 [N][K]) — independent of routing
  transpose_k<<<dim3(128, 32, NEXP), dim3(32, 8), 0, stream>>>(gate_up_w, wgu_t, DIM, 2 * FFD);
  transpose_k<<<dim3(32, 64, NEXP), dim3(32, 8), 0, stream>>>(down_w, wd_t, FFD, DIM);

  router_k<<<T_TOK, 64, 0, stream>>>(x, gate_w, out_logits, sel, selw);
  scan_k<<<1, 1024, 0, stream>>>(sel, pos, offs, rowtok, pairrow);
  gather_k<<<NRP, 256, 0, stream>>>(x, rowtok, xg);
  xa_k<<<NRP, 64, 0, stream>>>(xg, A_gate, A_up, offs, xa_g, xa_u);
  gemm1_k<<<dim3(32, MTILES), 256, 0, stream>>>(xg, wgu_t, gate_up_b, B_gate, B_up,
                                                xa_g, xa_u, offs, actb);
  aad_k<<<NRP, 64, 0, stream>>>(actb, A_down, offs, aad);
  gemm2_k<<<dim3(8, MTILES), 256, 0, stream>>>(actb, wd_t, down_b, B_down, aad, offs, downb);
  combine_k<<<T_TOK, 256, 0, stream>>>(downb, pairrow, selw, out_final);
}

// Round 3
// 302.902 us; speedup vs baseline: 1.2333x; 1.2333x over previous
//
#include <hip/hip_runtime.h>

#define T_TOK 4096
#define DIM   1024
#define FFD   2048
#define NEXP  4
#define NRP   8704      // 68*128 padded row capacity
#define MTILES 68

typedef unsigned short u16;
typedef __attribute__((ext_vector_type(8))) short short8;
typedef __attribute__((ext_vector_type(4))) float f32x4;
typedef __attribute__((ext_vector_type(8))) unsigned short u16x8;
typedef __attribute__((ext_vector_type(4))) unsigned short u16x4;

typedef __attribute__((address_space(1))) unsigned int as1_u32;
typedef __attribute__((address_space(3))) unsigned int as3_u32;

__device__ __forceinline__ u16 f2bf(float f) {
  union { float f; unsigned u; } v; v.f = f;
  unsigned u = v.u;
  return (u16)((u + 0x7fffu + ((u >> 16) & 1u)) >> 16);   // RNE
}
__device__ __forceinline__ float bf2f(u16 h) {
  union { unsigned u; float f; } v; v.u = ((unsigned)h) << 16;
  return v.f;
}
__device__ __forceinline__ void gload16(const void* g, void* l) {
  __builtin_amdgcn_global_load_lds((const as1_u32*)g, (as3_u32*)l, 16, 0, 0);
}

// ---------------- router: fp32 logits, softmax top-2, renorm ----------------
__global__ void router_k(const float* __restrict__ x, const float* __restrict__ gw,
                         float* __restrict__ logits_out, int* __restrict__ sel,
                         float* __restrict__ selw) {
  int t = blockIdx.x;
  int lane = threadIdx.x;           // block = 64 (one wave)
  float xv[16];
#pragma unroll
  for (int i = 0; i < 16; ++i) xv[i] = x[(size_t)t * DIM + lane + i * 64];
  float l[4];
#pragma unroll
  for (int e = 0; e < 4; ++e) {
    float s = 0.f;
#pragma unroll
    for (int i = 0; i < 16; ++i) s += xv[i] * gw[e * DIM + lane + i * 64];
#pragma unroll
    for (int off = 32; off > 0; off >>= 1) s += __shfl_xor(s, off, 64);
    l[e] = s;
  }
  if (lane == 0) {
#pragma unroll
    for (int e = 0; e < 4; ++e) logits_out[(size_t)t * 4 + e] = l[e];
    int e0 = 0; float b0 = l[0];
    for (int e = 1; e < 4; ++e) if (l[e] > b0) { b0 = l[e]; e0 = e; }
    int e1 = -1; float b1 = -3.4e38f;
    for (int e = 0; e < 4; ++e) if (e != e0 && l[e] > b1) { b1 = l[e]; e1 = e; }
    float p1 = expf(b1 - b0);
    float w0 = 1.f / (1.f + p1);
    sel[2 * t] = e0; sel[2 * t + 1] = e1;
    selw[2 * t] = w0; selw[2 * t + 1] = 1.f - w0;
  }
}

// ------------- deterministic bucket assignment (single block) ---------------
__global__ void scan_k(const int* __restrict__ sel, int* __restrict__ pos,
                       int* __restrict__ offs, int* __restrict__ rowtok,
                       int* __restrict__ pairrow) {
  __shared__ int base[4];
  __shared__ int wsum[16];
  __shared__ int off_s[5];
  int tid = threadIdx.x, lane = tid & 63, wid = tid >> 6;   // 1024 threads = 16 waves
  if (tid < 4) base[tid] = 0;
  __syncthreads();
  for (int chunk = 0; chunk < 4; ++chunk) {
    int t = chunk * 1024 + tid;
    int e0 = sel[2 * t], e1 = sel[2 * t + 1];
    for (int e = 0; e < 4; ++e) {
      bool f = (e0 == e) || (e1 == e);
      unsigned long long m = __ballot(f);
      int within = __popcll(m & ((1ull << lane) - 1ull));
      if (lane == 0) wsum[wid] = __popcll(m);
      __syncthreads();
      int wbase = 0, tot = 0;
      for (int i = 0; i < 16; ++i) { int v = wsum[i]; if (i < wid) wbase += v; tot += v; }
      if (f) {
        int p = base[e] + wbase + within;
        if (e0 == e) pos[2 * t] = p; else pos[2 * t + 1] = p;
      }
      __syncthreads();
      if (tid == 0) base[e] += tot;
      __syncthreads();
    }
  }
  if (tid == 0) {
    int o = 0;
    for (int e = 0; e < 4; ++e) { off_s[e] = o; o += ((base[e] + 127) >> 7) << 7; }
    off_s[4] = o;
    for (int i = 0; i < 5; ++i) offs[i] = off_s[i];
  }
  __syncthreads();
  for (int r = tid; r < NRP; r += 1024) rowtok[r] = -1;
  __syncthreads();
  for (int t = tid; t < T_TOK; t += 1024) {
#pragma unroll
    for (int s = 0; s < 2; ++s) {
      int e = sel[2 * t + s];
      int rr = off_s[e] + pos[2 * t + s];
      pairrow[2 * t + s] = rr;
      rowtok[rr] = t;
    }
  }
}

// ---------------- gather x rows (bucket order) -> bf16 ----------------------
__global__ void gather_k(const float* __restrict__ x, const int* __restrict__ rowtok,
                         u16* __restrict__ xg) {
  int r = blockIdx.x, tid = threadIdx.x;   // 256 threads, 4 floats each
  int t = rowtok[r];
  float4 v = make_float4(0.f, 0.f, 0.f, 0.f);
  if (t >= 0) v = ((const float4*)(x + (size_t)t * DIM))[tid];
  u16x4 o;
  o[0] = f2bf(v.x); o[1] = f2bf(v.y); o[2] = f2bf(v.z); o[3] = f2bf(v.w);
  ((u16x4*)(xg + (size_t)r * DIM))[tid] = o;
}

// -------- pre-convert LoRA A matrices to bf16 (abgu[4][32][1024], adb[4][16][2048])
__global__ void cvtA_k(const float* __restrict__ Ag, const float* __restrict__ Au,
                       const float* __restrict__ Ad, u16* __restrict__ abgu,
                       u16* __restrict__ adb) {
  int g = blockIdx.x * 256 + threadIdx.x;   // each handles 4 elements
  if (g < 32768) {
    int flat = g * 4;
    int e = flat >> 15;
    int rem = flat & 32767;
    int q = rem >> 10;
    int d = rem & 1023;
    const float* src = (q < 16) ? (Ag + ((size_t)e * 16 + q) * DIM + d)
                                : (Au + ((size_t)e * 16 + (q - 16)) * DIM + d);
    float4 v = *(const float4*)src;
    u16x4 o; o[0] = f2bf(v.x); o[1] = f2bf(v.y); o[2] = f2bf(v.z); o[3] = f2bf(v.w);
    *(u16x4*)(abgu + (size_t)flat) = o;
  } else {
    int flat = (g - 32768) * 4;
    float4 v = *(const float4*)(Ad + flat);
    u16x4 o; o[0] = f2bf(v.x); o[1] = f2bf(v.y); o[2] = f2bf(v.z); o[3] = f2bf(v.w);
    *(u16x4*)(adb + (size_t)flat) = o;
  }
}

// ---------------- per-row LoRA A-projections, 2 rows per wave ----------------
__global__ void xa_k(const u16* __restrict__ xg, const u16* __restrict__ abgu,
                     const int* __restrict__ offs, float* __restrict__ xagu) {
  int r0 = blockIdx.x * 2, lane = threadIdx.x;   // block = 64
  int e = 0;
  if (r0 >= offs[1]) e = 1;
  if (r0 >= offs[2]) e = 2;
  if (r0 >= offs[3]) e = 3;
  float x0[16], x1[16];
#pragma unroll
  for (int i = 0; i < 4; ++i) {
    u16x4 v0 = ((const u16x4*)(xg + (size_t)r0 * DIM))[lane + i * 64];
    u16x4 v1 = ((const u16x4*)(xg + (size_t)(r0 + 1) * DIM))[lane + i * 64];
#pragma unroll
    for (int j = 0; j < 4; ++j) { x0[i * 4 + j] = bf2f(v0[j]); x1[i * 4 + j] = bf2f(v1[j]); }
  }
  const u16* A = abgu + (size_t)e * 32 * DIM;
  for (int q = 0; q < 32; ++q) {
    float s0 = 0.f, s1 = 0.f;
#pragma unroll
    for (int i = 0; i < 4; ++i) {
      u16x4 av = ((const u16x4*)(A + (size_t)q * DIM))[lane + i * 64];
#pragma unroll
      for (int j = 0; j < 4; ++j) {
        float a = bf2f(av[j]);
        s0 += x0[i * 4 + j] * a; s1 += x1[i * 4 + j] * a;
      }
    }
#pragma unroll
    for (int off = 32; off > 0; off >>= 1) { s0 += __shfl_xor(s0, off, 64); s1 += __shfl_xor(s1, off, 64); }
    if (lane == 0) { xagu[(size_t)r0 * 32 + q] = s0; xagu[(size_t)(r0 + 1) * 32 + q] = s1; }
  }
}

__global__ void aad_k(const u16* __restrict__ act, const u16* __restrict__ adb,
                      const int* __restrict__ offs, float* __restrict__ aad) {
  int r0 = blockIdx.x * 2, lane = threadIdx.x;
  int e = 0;
  if (r0 >= offs[1]) e = 1;
  if (r0 >= offs[2]) e = 2;
  if (r0 >= offs[3]) e = 3;
  float x0[32], x1[32];
#pragma unroll
  for (int i = 0; i < 8; ++i) {
    u16x4 v0 = ((const u16x4*)(act + (size_t)r0 * FFD))[lane + i * 64];
    u16x4 v1 = ((const u16x4*)(act + (size_t)(r0 + 1) * FFD))[lane + i * 64];
#pragma unroll
    for (int j = 0; j < 4; ++j) { x0[i * 4 + j] = bf2f(v0[j]); x1[i * 4 + j] = bf2f(v1[j]); }
  }
  const u16* A = adb + (size_t)e * 16 * FFD;
  for (int q = 0; q < 16; ++q) {
    float s0 = 0.f, s1 = 0.f;
#pragma unroll
    for (int i = 0; i < 8; ++i) {
      u16x4 av = ((const u16x4*)(A + (size_t)q * FFD))[lane + i * 64];
#pragma unroll
      for (int j = 0; j < 4; ++j) {
        float a = bf2f(av[j]);
        s0 += x0[i * 4 + j] * a; s1 += x1[i * 4 + j] * a;
      }
    }
#pragma unroll
    for (int off = 32; off > 0; off >>= 1) { s0 += __shfl_xor(s0, off, 64); s1 += __shfl_xor(s1, off, 64); }
    if (lane == 0) { aad[(size_t)r0 * 16 + q] = s0; aad[(size_t)(r0 + 1) * 16 + q] = s1; }
  }
}

// ---------------- weight transpose fp32[K][N] -> bf16[N][K] ------------------
__global__ void transpose_k(const float* __restrict__ in, u16* __restrict__ out,
                            int K, int N) {
  int e = blockIdx.z;
  int n0 = blockIdx.x * 32, k0 = blockIdx.y * 32;
  const float* I = in + (size_t)e * K * N;
  u16* O = out + (size_t)e * N * K;
  __shared__ u16 tile[32][33];
#pragma unroll
  for (int i = 0; i < 4; ++i) {
    int k = k0 + threadIdx.y + i * 8;
    tile[threadIdx.y + i * 8][threadIdx.x] = f2bf(I[(size_t)k * N + n0 + threadIdx.x]);
  }
  __syncthreads();
#pragma unroll
  for (int i = 0; i < 4; ++i) {
    int n = n0 + threadIdx.y + i * 8;
    O[(size_t)n * K + k0 + threadIdx.x] = tile[threadIdx.x][threadIdx.y + i * 8];
  }
}

// ---------------- GEMM1: act = swiglu(x@Wgu + b + lora), T2+T1 swizzled -----
__global__ __launch_bounds__(256) void gemm1_k(
    const u16* __restrict__ xg, const u16* __restrict__ wgu_t,
    const float* __restrict__ gub, const float* __restrict__ Bg,
    const float* __restrict__ Bu, const float* __restrict__ xagu,
    const int* __restrict__ offs, u16* __restrict__ act) {
  __shared__ __align__(16) u16 sAB[8192];
  u16* sA = sAB;          // [128][32] swizzled: (r,kblk) at kblk^((r>>1)&3)
  u16* sB = sAB + 4096;   // [128][32]  rows 0..63 gate, 64..127 up
  int tid = threadIdx.x, w = tid >> 6, lane = tid & 63;
  int orig = blockIdx.x;                      // T1: bijective XCD swizzle, 2176 = 8*272
  int wg = (orig & 7) * 272 + (orig >> 3);
  int f0 = (wg & 31) * 64;
  int row0 = (wg >> 5) * 128;
  int e = 0;
  if (row0 >= offs[1]) e = 1;
  if (row0 >= offs[2]) e = 2;
  if (row0 >= offs[3]) e = 3;

  int srow = w * 32 + (lane >> 2);
  int scol = ((lane & 3) ^ ((lane >> 3) & 3)) * 8;     // pre-swizzled global source (T2)
  const u16* gA = xg + (size_t)(row0 + srow) * DIM + scol;
  int n1 = srow, n2 = srow + 16;
  int gr1 = (n1 < 64) ? (f0 + n1) : (2048 + f0 + n1 - 64);
  int gr2 = (n2 < 64) ? (f0 + n2) : (2048 + f0 + n2 - 64);
  const u16* gB1 = wgu_t + ((size_t)e << 22) + (size_t)gr1 * DIM + scol;
  const u16* gB2 = wgu_t + ((size_t)e << 22) + (size_t)gr2 * DIM + scol;
  u16* lA = sA + w * 1024;
  u16* lB = sB + w * 1024;
  int fo = (((lane >> 4) ^ ((lane >> 1) & 3))) * 8;    // swizzled fragment k-offset

  f32x4 acc[2][8];
#pragma unroll
  for (int i = 0; i < 2; ++i)
#pragma unroll
    for (int j = 0; j < 8; ++j) acc[i][j] = f32x4{0.f, 0.f, 0.f, 0.f};

  for (int kk = 0; kk < DIM; kk += 32) {
    __syncthreads();
    gload16(gA + kk, lA);
    gload16(gA + 16 * DIM + kk, lA + 512);
    gload16(gB1 + kk, lB);
    gload16(gB2 + kk, lB + 512);
    __syncthreads();
    short8 a[2], b[8];
#pragma unroll
    for (int mi = 0; mi < 2; ++mi)
      a[mi] = *(const short8*)&sA[(w * 32 + mi * 16 + (lane & 15)) * 32 + fo];
#pragma unroll
    for (int ni = 0; ni < 8; ++ni)
      b[ni] = *(const short8*)&sB[(ni * 16 + (lane & 15)) * 32 + fo];
#pragma unroll
    for (int mi = 0; mi < 2; ++mi)
#pragma unroll
      for (int ni = 0; ni < 8; ++ni)
        acc[mi][ni] = __builtin_amdgcn_mfma_f32_16x16x32_bf16(a[mi], b[ni], acc[mi][ni], 0, 0, 0);
  }

  // ---- LoRA + bias as one extra K=32 MFMA step: k0..15 = 2*xa / B, k16 = 1/bias ----
  __syncthreads();
  {
    int r = tid >> 1, kh = tid & 1;
    int sw = (r >> 1) & 3;
    int o0 = r * 32 + ((2 * kh + 0) ^ sw) * 8;
    int o1 = r * 32 + ((2 * kh + 1) ^ sw) * 8;
    u16 tmp[16];
    if (kh == 0) {
#pragma unroll
      for (int q = 0; q < 16; ++q) tmp[q] = f2bf(2.f * xagu[(size_t)(row0 + r) * 32 + q]);
    } else {
#pragma unroll
      for (int q = 0; q < 16; ++q) tmp[q] = 0;
      tmp[0] = 0x3f80;   // 1.0 at k=16
    }
    *(u16x8*)&sA[o0] = *(u16x8*)&tmp[0];
    *(u16x8*)&sA[o1] = *(u16x8*)&tmp[8];
    int f = (r < 64) ? (f0 + r) : (f0 + r - 64);
    const float* Bsrc = (r < 64) ? Bg : Bu;
    float bias = gub[e * 4096 + ((r < 64) ? f : (2048 + f))];
    if (kh == 0) {
#pragma unroll
      for (int q = 0; q < 16; ++q) tmp[q] = f2bf(Bsrc[((size_t)e * FFD + f) * 16 + q]);
    } else {
#pragma unroll
      for (int q = 0; q < 16; ++q) tmp[q] = 0;
      tmp[0] = f2bf(bias);
    }
    *(u16x8*)&sB[o0] = *(u16x8*)&tmp[0];
    *(u16x8*)&sB[o1] = *(u16x8*)&tmp[8];
  }
  __syncthreads();
  {  // gate half
    short8 a[2], b[4];
#pragma unroll
    for (int mi = 0; mi < 2; ++mi)
      a[mi] = *(const short8*)&sA[(w * 32 + mi * 16 + (lane & 15)) * 32 + fo];
#pragma unroll
    for (int ni = 0; ni < 4; ++ni)
      b[ni] = *(const short8*)&sB[(ni * 16 + (lane & 15)) * 32 + fo];
#pragma unroll
    for (int mi = 0; mi < 2; ++mi)
#pragma unroll
      for (int ni = 0; ni < 4; ++ni)
        acc[mi][ni] = __builtin_amdgcn_mfma_f32_16x16x32_bf16(a[mi], b[ni], acc[mi][ni], 0, 0, 0);
  }
  __syncthreads();
  {  // swap A-lora to xa_up
    int r = tid >> 1, kh = tid & 1;
    int sw = (r >> 1) & 3;
    int o0 = r * 32 + ((2 * kh + 0) ^ sw) * 8;
    int o1 = r * 32 + ((2 * kh + 1) ^ sw) * 8;
    u16 tmp[16];
    if (kh == 0) {
#pragma unroll
      for (int q = 0; q < 16; ++q) tmp[q] = f2bf(2.f * xagu[(size_t)(row0 + r) * 32 + 16 + q]);
    } else {
#pragma unroll
      for (int q = 0; q < 16; ++q) tmp[q] = 0;
      tmp[0] = 0x3f80;
    }
    *(u16x8*)&sA[o0] = *(u16x8*)&tmp[0];
    *(u16x8*)&sA[o1] = *(u16x8*)&tmp[8];
  }
  __syncthreads();
  {  // up half
    short8 a[2], b[4];
#pragma unroll
    for (int mi = 0; mi < 2; ++mi)
      a[mi] = *(const short8*)&sA[(w * 32 + mi * 16 + (lane & 15)) * 32 + fo];
#pragma unroll
    for (int ni = 0; ni < 4; ++ni)
      b[ni] = *(const short8*)&sB[((ni + 4) * 16 + (lane & 15)) * 32 + fo];
#pragma unroll
    for (int mi = 0; mi < 2; ++mi)
#pragma unroll
      for (int ni = 0; ni < 4; ++ni)
        acc[mi][ni + 4] = __builtin_amdgcn_mfma_f32_16x16x32_bf16(a[mi], b[ni], acc[mi][ni + 4], 0, 0, 0);
  }
  __syncthreads();
  // ---- register-local SwiGLU, repack through LDS for coalesced bf16 store ----
#pragma unroll
  for (int mi = 0; mi < 2; ++mi)
#pragma unroll
    for (int ni = 0; ni < 4; ++ni)
#pragma unroll
      for (int j = 0; j < 4; ++j) {
        int lr = w * 32 + mi * 16 + (lane >> 4) * 4 + j;
        int lc = ni * 16 + (lane & 15);
        float g = acc[mi][ni][j];
        float u = acc[mi][ni + 4][j];
        float s = g / (1.f + __expf(-g));
        sAB[lr * 64 + lc] = f2bf(s * u);
      }
  __syncthreads();
#pragma unroll
  for (int it = 0; it < 4; ++it) {
    int idx = it * 256 + tid;
    int rr = idx >> 3, c8 = (idx & 7) * 8;
    *(u16x8*)(act + (size_t)(row0 + rr) * FFD + f0 + c8) = *(const u16x8*)&sAB[rr * 64 + c8];
  }
}

// ------- GEMM2: down = act@Wd + b + lora; split-K=2, bf16 partials ----------
__global__ __launch_bounds__(256) void gemm2_k(
    const u16* __restrict__ act, const u16* __restrict__ wd_t,
    const float* __restrict__ db, const float* __restrict__ Bd,
    const float* __restrict__ aad, const int* __restrict__ offs,
    u16* __restrict__ down) {
  __shared__ __align__(16) u16 sAB[8192];
  u16* sA = sAB;
  u16* sB = sAB + 4096;
  int tid = threadIdx.x, w = tid >> 6, lane = tid & 63;
  int orig = blockIdx.x;                      // T1: 544 = 8*68 bijective
  int wg = (orig & 7) * 68 + (orig >> 3);
  int n0 = (wg & 7) * 128;
  int row0 = (wg >> 3) * 128;
  int ks = blockIdx.y;
  size_t kbase = (size_t)ks * 1024;
  int e = 0;
  if (row0 >= offs[1]) e = 1;
  if (row0 >= offs[2]) e = 2;
  if (row0 >= offs[3]) e = 3;
  int wm = w >> 1, wn = w & 1;

  int srow = w * 32 + (lane >> 2);
  int scol = ((lane & 3) ^ ((lane >> 3) & 3)) * 8;
  const u16* gA = act + (size_t)(row0 + srow) * FFD + kbase + scol;
  const u16* gB = wd_t + (size_t)e * DIM * FFD + (size_t)(n0 + srow) * FFD + kbase + scol;
  u16* lA = sA + w * 1024;
  u16* lB = sB + w * 1024;
  int fo = (((lane >> 4) ^ ((lane >> 1) & 3))) * 8;

  f32x4 acc[4][4];
#pragma unroll
  for (int i = 0; i < 4; ++i)
#pragma unroll
    for (int j = 0; j < 4; ++j) acc[i][j] = f32x4{0.f, 0.f, 0.f, 0.f};

  for (int kk = 0; kk < 1024; kk += 32) {
    __syncthreads();
    gload16(gA + kk, lA);
    gload16(gA + 16 * FFD + kk, lA + 512);
    gload16(gB + kk, lB);
    gload16(gB + 16 * FFD + kk, lB + 512);
    __syncthreads();
    short8 a[4], b[4];
#pragma unroll
    for (int mi = 0; mi < 4; ++mi)
      a[mi] = *(const short8*)&sA[(wm * 64 + mi * 16 + (lane & 15)) * 32 + fo];
#pragma unroll
    for (int ni = 0; ni < 4; ++ni)
      b[ni] = *(const short8*)&sB[(wn * 64 + ni * 16 + (lane & 15)) * 32 + fo];
#pragma unroll
    for (int mi = 0; mi < 4; ++mi)
#pragma unroll
      for (int ni = 0; ni < 4; ++ni)
        acc[mi][ni] = __builtin_amdgcn_mfma_f32_16x16x32_bf16(a[mi], b[ni], acc[mi][ni], 0, 0, 0);
  }

  if (ks == 0) {
    // ---- LoRA-down + bias as one extra K=32 MFMA step (half 0 only) ----
    __syncthreads();
    {
      int r = tid >> 1, kh = tid & 1;
      int sw = (r >> 1) & 3;
      int o0 = r * 32 + ((2 * kh + 0) ^ sw) * 8;
      int o1 = r * 32 + ((2 * kh + 1) ^ sw) * 8;
      u16 tmp[16];
      if (kh == 0) {
#pragma unroll
        for (int q = 0; q < 16; ++q) tmp[q] = f2bf(2.f * aad[(size_t)(row0 + r) * 16 + q]);
      } else {
#pragma unroll
        for (int q = 0; q < 16; ++q) tmp[q] = 0;
        tmp[0] = 0x3f80;
      }
      *(u16x8*)&sA[o0] = *(u16x8*)&tmp[0];
      *(u16x8*)&sA[o1] = *(u16x8*)&tmp[8];
      if (kh == 0) {
#pragma unroll
        for (int q = 0; q < 16; ++q) tmp[q] = f2bf(Bd[((size_t)e * DIM + n0 + r) * 16 + q]);
      } else {
#pragma unroll
        for (int q = 0; q < 16; ++q) tmp[q] = 0;
        tmp[0] = f2bf(db[e * DIM + n0 + r]);
      }
      *(u16x8*)&sB[o0] = *(u16x8*)&tmp[0];
      *(u16x8*)&sB[o1] = *(u16x8*)&tmp[8];
    }
    __syncthreads();
    {
      short8 a[4], b[4];
#pragma unroll
      for (int mi = 0; mi < 4; ++mi)
        a[mi] = *(const short8*)&sA[(wm * 64 + mi * 16 + (lane & 15)) * 32 + fo];
#pragma unroll
      for (int ni = 0; ni < 4; ++ni)
        b[ni] = *(const short8*)&sB[(wn * 64 + ni * 16 + (lane & 15)) * 32 + fo];
#pragma unroll
      for (int mi = 0; mi < 4; ++mi)
#pragma unroll
        for (int ni = 0; ni < 4; ++ni)
          acc[mi][ni] = __builtin_amdgcn_mfma_f32_16x16x32_bf16(a[mi], b[ni], acc[mi][ni], 0, 0, 0);
    }
  }
  // ---- store bf16 partial ----
#pragma unroll
  for (int mi = 0; mi < 4; ++mi)
#pragma unroll
    for (int ni = 0; ni < 4; ++ni)
#pragma unroll
      for (int j = 0; j < 4; ++j) {
        int lr = wm * 64 + mi * 16 + (lane >> 4) * 4 + j;
        int lc = wn * 64 + ni * 16 + (lane & 15);
        down[((size_t)ks * NRP + row0 + lr) * DIM + n0 + lc] = f2bf(acc[mi][ni][j]);
      }
}

// ---------------- weighted combine (sums split-K halves) --------------------
__global__ void combine_k(const u16* __restrict__ down, const int* __restrict__ pairrow,
                          const float* __restrict__ selw, float* __restrict__ out) {
  int t = blockIdx.x, tid = threadIdx.x;   // 256 threads, 4 cols each
  int r0 = pairrow[2 * t], r1 = pairrow[2 * t + 1];
  float w0 = selw[2 * t], w1 = selw[2 * t + 1];
  u16x4 a0 = *(const u16x4*)(down + ((size_t)r0) * DIM + tid * 4);
  u16x4 a1 = *(const u16x4*)(down + ((size_t)NRP + r0) * DIM + tid * 4);
  u16x4 b0 = *(const u16x4*)(down + ((size_t)r1) * DIM + tid * 4);
  u16x4 b1 = *(const u16x4*)(down + ((size_t)NRP + r1) * DIM + tid * 4);
  f32x4 o;
#pragma unroll
  for (int j = 0; j < 4; ++j)
    o[j] = w0 * (bf2f(a0[j]) + bf2f(a1[j])) + w1 * (bf2f(b0[j]) + bf2f(b1[j]));
  *(f32x4*)(out + (size_t)t * DIM + tid * 4) = o;
}

extern "C" void kernel_launch(void* const* d_in, const int* in_sizes, int n_in,
                              void* d_out, int out_size, void* d_ws, size_t ws_size,
                              hipStream_t stream) {
  const float* x         = (const float*)d_in[0];
  const float* gate_w    = (const float*)d_in[1];
  const float* gate_up_w = (const float*)d_in[2];
  const float* gate_up_b = (const float*)d_in[3];
  const float* down_w    = (const float*)d_in[4];
  const float* down_b    = (const float*)d_in[5];
  const float* A_gate    = (const float*)d_in[6];
  const float* B_gate    = (const float*)d_in[7];
  const float* A_up      = (const float*)d_in[8];
  const float* B_up      = (const float*)d_in[9];
  const float* A_down    = (const float*)d_in[10];
  const float* B_down    = (const float*)d_in[11];

  float* out_final  = (float*)d_out;
  float* out_logits = out_final + (size_t)T_TOK * DIM;

  char* ws = (char*)d_ws;
  size_t o = 0;
  auto take = [&](size_t bytes) -> void* {
    void* p = ws + o;
    o = (o + bytes + 255) & ~(size_t)255;
    return p;
  };
  int*   offs    = (int*)take(64);
  int*   sel     = (int*)take((size_t)T_TOK * 2 * 4);
  float* selw    = (float*)take((size_t)T_TOK * 2 * 4);
  int*   pos     = (int*)take((size_t)T_TOK * 2 * 4);
  int*   pairrow = (int*)take((size_t)T_TOK * 2 * 4);
  int*   rowtok  = (int*)take((size_t)NRP * 4);
  float* xagu    = (float*)take((size_t)NRP * 32 * 4);
  float* aadb    = (float*)take((size_t)NRP * 16 * 4);
  u16*   abgu    = (u16*)take((size_t)NEXP * 32 * DIM * 2);
  u16*   adb     = (u16*)take((size_t)NEXP * 16 * FFD * 2);
  u16*   xg      = (u16*)take((size_t)NRP * DIM * 2);
  u16*   actb    = (u16*)take((size_t)NRP * FFD * 2);
  u16*   downb   = (u16*)take((size_t)2 * NRP * DIM * 2);
  u16*   wgu_t   = (u16*)take((size_t)NEXP * 2 * FFD * DIM * 2);
  u16*   wd_t    = (u16*)take((size_t)NEXP * DIM * FFD * 2);
  (void)ws_size; (void)in_sizes; (void)n_in; (void)out_size;

  // weight transposes (fp32 [K][N] -> bf16 [N][K]) — independent of routing
  transpose_k<<<dim3(128, 32, NEXP), dim3(32, 8), 0, stream>>>(gate_up_w, wgu_t, DIM, 2 * FFD);
  transpose_k<<<dim3(32, 64, NEXP), dim3(32, 8), 0, stream>>>(down_w, wd_t, FFD, DIM);
  cvtA_k<<<256, 256, 0, stream>>>(A_gate, A_up, A_down, abgu, adb);

  router_k<<<T_TOK, 64, 0, stream>>>(x, gate_w, out_logits, sel, selw);
  scan_k<<<1, 1024, 0, stream>>>(sel, pos, offs, rowtok, pairrow);
  gather_k<<<NRP, 256, 0, stream>>>(x, rowtok, xg);
  xa_k<<<NRP / 2, 64, 0, stream>>>(xg, abgu, offs, xagu);
  gemm1_k<<<2176, 256, 0, stream>>>(xg, wgu_t, gate_up_b, B_gate, B_up, xagu, offs, actb);
  aad_k<<<NRP / 2, 64, 0, stream>>>(actb, adb, offs, aadb);
  gemm2_k<<<dim3(544, 2), 256, 0, stream>>>(actb, wd_t, down_b, B_down, aadb, offs, downb);
  combine_k<<<T_TOK, 256, 0, stream>>>(downb, pairrow, selw, out_final);
}

// Round 4
// 289.728 us; speedup vs baseline: 1.2894x; 1.0455x over previous
//
#include <hip/hip_runtime.h>

#define T_TOK 4096
#define DIM   1024
#define FFD   2048
#define NEXP  4
#define NRP   8704      // 68*128 padded row capacity
#define MTILES 68

typedef unsigned short u16;
typedef __attribute__((ext_vector_type(8))) short short8;
typedef __attribute__((ext_vector_type(4))) float f32x4;
typedef __attribute__((ext_vector_type(8))) unsigned short u16x8;
typedef __attribute__((ext_vector_type(4))) unsigned short u16x4;

typedef __attribute__((address_space(1))) unsigned int as1_u32;
typedef __attribute__((address_space(3))) unsigned int as3_u32;

__device__ __forceinline__ u16 f2bf(float f) {
  union { float f; unsigned u; } v; v.f = f;
  unsigned u = v.u;
  return (u16)((u + 0x7fffu + ((u >> 16) & 1u)) >> 16);   // RNE
}
__device__ __forceinline__ float bf2f(u16 h) {
  union { unsigned u; float f; } v; v.u = ((unsigned)h) << 16;
  return v.f;
}
__device__ __forceinline__ void gload16(const void* g, void* l) {
  __builtin_amdgcn_global_load_lds((const as1_u32*)g, (as3_u32*)l, 16, 0, 0);
}

// ---------------- router: fp32 logits, softmax top-2, renorm ----------------
__global__ void router_k(const float* __restrict__ x, const float* __restrict__ gw,
                         float* __restrict__ logits_out, int* __restrict__ sel,
                         float* __restrict__ selw) {
  int t = blockIdx.x;
  int lane = threadIdx.x;           // block = 64 (one wave)
  float xv[16];
#pragma unroll
  for (int i = 0; i < 16; ++i) xv[i] = x[(size_t)t * DIM + lane + i * 64];
  float l[4];
#pragma unroll
  for (int e = 0; e < 4; ++e) {
    float s = 0.f;
#pragma unroll
    for (int i = 0; i < 16; ++i) s += xv[i] * gw[e * DIM + lane + i * 64];
#pragma unroll
    for (int off = 32; off > 0; off >>= 1) s += __shfl_xor(s, off, 64);
    l[e] = s;
  }
  if (lane == 0) {
#pragma unroll
    for (int e = 0; e < 4; ++e) logits_out[(size_t)t * 4 + e] = l[e];
    int e0 = 0; float b0 = l[0];
    for (int e = 1; e < 4; ++e) if (l[e] > b0) { b0 = l[e]; e0 = e; }
    int e1 = -1; float b1 = -3.4e38f;
    for (int e = 0; e < 4; ++e) if (e != e0 && l[e] > b1) { b1 = l[e]; e1 = e; }
    float p1 = expf(b1 - b0);
    float w0 = 1.f / (1.f + p1);
    sel[2 * t] = e0; sel[2 * t + 1] = e1;
    selw[2 * t] = w0; selw[2 * t + 1] = 1.f - w0;
  }
}

// ------------- deterministic bucket assignment (single block) ---------------
__global__ void scan_k(const int* __restrict__ sel, int* __restrict__ pos,
                       int* __restrict__ offs, int* __restrict__ rowtok,
                       int* __restrict__ pairrow) {
  __shared__ int base[4];
  __shared__ int wsum[16];
  __shared__ int off_s[5];
  int tid = threadIdx.x, lane = tid & 63, wid = tid >> 6;   // 1024 threads = 16 waves
  if (tid < 4) base[tid] = 0;
  __syncthreads();
  for (int chunk = 0; chunk < 4; ++chunk) {
    int t = chunk * 1024 + tid;
    int e0 = sel[2 * t], e1 = sel[2 * t + 1];
    for (int e = 0; e < 4; ++e) {
      bool f = (e0 == e) || (e1 == e);
      unsigned long long m = __ballot(f);
      int within = __popcll(m & ((1ull << lane) - 1ull));
      if (lane == 0) wsum[wid] = __popcll(m);
      __syncthreads();
      int wbase = 0, tot = 0;
      for (int i = 0; i < 16; ++i) { int v = wsum[i]; if (i < wid) wbase += v; tot += v; }
      if (f) {
        int p = base[e] + wbase + within;
        if (e0 == e) pos[2 * t] = p; else pos[2 * t + 1] = p;
      }
      __syncthreads();
      if (tid == 0) base[e] += tot;
      __syncthreads();
    }
  }
  if (tid == 0) {
    int o = 0;
    for (int e = 0; e < 4; ++e) { off_s[e] = o; o += ((base[e] + 127) >> 7) << 7; }
    off_s[4] = o;
    for (int i = 0; i < 5; ++i) offs[i] = off_s[i];
  }
  __syncthreads();
  for (int r = tid; r < NRP; r += 1024) rowtok[r] = -1;
  __syncthreads();
  for (int t = tid; t < T_TOK; t += 1024) {
#pragma unroll
    for (int s = 0; s < 2; ++s) {
      int e = sel[2 * t + s];
      int rr = off_s[e] + pos[2 * t + s];
      pairrow[2 * t + s] = rr;
      rowtok[rr] = t;
    }
  }
}

// ---------------- gather x rows (bucket order) -> bf16 ----------------------
__global__ void gather_k(const float* __restrict__ x, const int* __restrict__ rowtok,
                         u16* __restrict__ xg) {
  int r = blockIdx.x, tid = threadIdx.x;   // 256 threads, 4 floats each
  int t = rowtok[r];
  float4 v = make_float4(0.f, 0.f, 0.f, 0.f);
  if (t >= 0) v = ((const float4*)(x + (size_t)t * DIM))[tid];
  u16x4 o;
  o[0] = f2bf(v.x); o[1] = f2bf(v.y); o[2] = f2bf(v.z); o[3] = f2bf(v.w);
  ((u16x4*)(xg + (size_t)r * DIM))[tid] = o;
}

// -------- pre-convert LoRA A matrices to bf16 (abgu[4][32][1024], adb[4][16][2048])
__global__ void cvtA_k(const float* __restrict__ Ag, const float* __restrict__ Au,
                       const float* __restrict__ Ad, u16* __restrict__ abgu,
                       u16* __restrict__ adb) {
  int g = blockIdx.x * 256 + threadIdx.x;   // each handles 4 elements
  if (g < 32768) {
    int flat = g * 4;
    int e = flat >> 15;
    int rem = flat & 32767;
    int q = rem >> 10;
    int d = rem & 1023;
    const float* src = (q < 16) ? (Ag + ((size_t)e * 16 + q) * DIM + d)
                                : (Au + ((size_t)e * 16 + (q - 16)) * DIM + d);
    float4 v = *(const float4*)src;
    u16x4 o; o[0] = f2bf(v.x); o[1] = f2bf(v.y); o[2] = f2bf(v.z); o[3] = f2bf(v.w);
    *(u16x4*)(abgu + (size_t)flat) = o;
  } else {
    int flat = (g - 32768) * 4;
    float4 v = *(const float4*)(Ad + flat);
    u16x4 o; o[0] = f2bf(v.x); o[1] = f2bf(v.y); o[2] = f2bf(v.z); o[3] = f2bf(v.w);
    *(u16x4*)(adb + (size_t)flat) = o;
  }
}

// ---------------- per-row LoRA A-projections, 2 rows per wave ----------------
__global__ void xa_k(const u16* __restrict__ xg, const u16* __restrict__ abgu,
                     const int* __restrict__ offs, float* __restrict__ xagu) {
  int r0 = blockIdx.x * 2, lane = threadIdx.x;   // block = 64
  int e = 0;
  if (r0 >= offs[1]) e = 1;
  if (r0 >= offs[2]) e = 2;
  if (r0 >= offs[3]) e = 3;
  float x0[16], x1[16];
#pragma unroll
  for (int i = 0; i < 4; ++i) {
    u16x4 v0 = ((const u16x4*)(xg + (size_t)r0 * DIM))[lane + i * 64];
    u16x4 v1 = ((const u16x4*)(xg + (size_t)(r0 + 1) * DIM))[lane + i * 64];
#pragma unroll
    for (int j = 0; j < 4; ++j) { x0[i * 4 + j] = bf2f(v0[j]); x1[i * 4 + j] = bf2f(v1[j]); }
  }
  const u16* A = abgu + (size_t)e * 32 * DIM;
  for (int q = 0; q < 32; ++q) {
    float s0 = 0.f, s1 = 0.f;
#pragma unroll
    for (int i = 0; i < 4; ++i) {
      u16x4 av = ((const u16x4*)(A + (size_t)q * DIM))[lane + i * 64];
#pragma unroll
      for (int j = 0; j < 4; ++j) {
        float a = bf2f(av[j]);
        s0 += x0[i * 4 + j] * a; s1 += x1[i * 4 + j] * a;
      }
    }
#pragma unroll
    for (int off = 32; off > 0; off >>= 1) { s0 += __shfl_xor(s0, off, 64); s1 += __shfl_xor(s1, off, 64); }
    if (lane == 0) { xagu[(size_t)r0 * 32 + q] = s0; xagu[(size_t)(r0 + 1) * 32 + q] = s1; }
  }
}

__global__ void aad_k(const u16* __restrict__ act, const u16* __restrict__ adb,
                      const int* __restrict__ offs, float* __restrict__ aad) {
  int r0 = blockIdx.x * 2, lane = threadIdx.x;
  int e = 0;
  if (r0 >= offs[1]) e = 1;
  if (r0 >= offs[2]) e = 2;
  if (r0 >= offs[3]) e = 3;
  float x0[32], x1[32];
#pragma unroll
  for (int i = 0; i < 8; ++i) {
    u16x4 v0 = ((const u16x4*)(act + (size_t)r0 * FFD))[lane + i * 64];
    u16x4 v1 = ((const u16x4*)(act + (size_t)(r0 + 1) * FFD))[lane + i * 64];
#pragma unroll
    for (int j = 0; j < 4; ++j) { x0[i * 4 + j] = bf2f(v0[j]); x1[i * 4 + j] = bf2f(v1[j]); }
  }
  const u16* A = adb + (size_t)e * 16 * FFD;
  for (int q = 0; q < 16; ++q) {
    float s0 = 0.f, s1 = 0.f;
#pragma unroll
    for (int i = 0; i < 8; ++i) {
      u16x4 av = ((const u16x4*)(A + (size_t)q * FFD))[lane + i * 64];
#pragma unroll
      for (int j = 0; j < 4; ++j) {
        float a = bf2f(av[j]);
        s0 += x0[i * 4 + j] * a; s1 += x1[i * 4 + j] * a;
      }
    }
#pragma unroll
    for (int off = 32; off > 0; off >>= 1) { s0 += __shfl_xor(s0, off, 64); s1 += __shfl_xor(s1, off, 64); }
    if (lane == 0) { aad[(size_t)r0 * 16 + q] = s0; aad[(size_t)(r0 + 1) * 16 + q] = s1; }
  }
}

// ---------------- weight transpose fp32[K][N] -> bf16[N][K] ------------------
__global__ void transpose_k(const float* __restrict__ in, u16* __restrict__ out,
                            int K, int N) {
  int e = blockIdx.z;
  int n0 = blockIdx.x * 32, k0 = blockIdx.y * 32;
  const float* I = in + (size_t)e * K * N;
  u16* O = out + (size_t)e * N * K;
  __shared__ u16 tile[32][33];
#pragma unroll
  for (int i = 0; i < 4; ++i) {
    int k = k0 + threadIdx.y + i * 8;
    tile[threadIdx.y + i * 8][threadIdx.x] = f2bf(I[(size_t)k * N + n0 + threadIdx.x]);
  }
  __syncthreads();
#pragma unroll
  for (int i = 0; i < 4; ++i) {
    int n = n0 + threadIdx.y + i * 8;
    O[(size_t)n * K + k0 + threadIdx.x] = tile[threadIdx.x][threadIdx.y + i * 8];
  }
}

// ---------------- GEMM1: act = swiglu(x@Wgu + b + lora) ---------------------
// 2-phase pipeline: double-buffered LDS, prefetch next K-step before compute,
// ONE __syncthreads per K-step (its vmcnt drain covers loads issued a full
// compute-phase earlier). T2 LDS swizzle kept; T1 removed (fetch regression).
__global__ __launch_bounds__(256) void gemm1_k(
    const u16* __restrict__ xg, const u16* __restrict__ wgu_t,
    const float* __restrict__ gub, const float* __restrict__ Bg,
    const float* __restrict__ Bu, const float* __restrict__ xagu,
    const int* __restrict__ offs, u16* __restrict__ act) {
  __shared__ __align__(16) u16 sAB[16384];   // 2 buffers x (A 4K + B 4K) u16
  int tid = threadIdx.x, w = tid >> 6, lane = tid & 63;
  int f0 = blockIdx.x * 64;
  int row0 = blockIdx.y * 128;
  int e = 0;
  if (row0 >= offs[1]) e = 1;
  if (row0 >= offs[2]) e = 2;
  if (row0 >= offs[3]) e = 3;

  int srow = w * 32 + (lane >> 2);
  int scol = ((lane & 3) ^ ((lane >> 3) & 3)) * 8;     // pre-swizzled global source (T2)
  const u16* gA = xg + (size_t)(row0 + srow) * DIM + scol;
  int n1 = srow, n2 = srow + 16;
  int gr1 = (n1 < 64) ? (f0 + n1) : (2048 + f0 + n1 - 64);
  int gr2 = (n2 < 64) ? (f0 + n2) : (2048 + f0 + n2 - 64);
  const u16* gB1 = wgu_t + ((size_t)e << 22) + (size_t)gr1 * DIM + scol;
  const u16* gB2 = wgu_t + ((size_t)e << 22) + (size_t)gr2 * DIM + scol;
  int fo = (((lane >> 4) ^ ((lane >> 1) & 3))) * 8;    // swizzled fragment k-offset
  int ar = (w * 32 + (lane & 15)) * 32 + fo;           // A-frag base (row stride 32)

  f32x4 acc[2][8];
#pragma unroll
  for (int i = 0; i < 2; ++i)
#pragma unroll
    for (int j = 0; j < 8; ++j) acc[i][j] = f32x4{0.f, 0.f, 0.f, 0.f};

  // prologue: stage K-step 0 into buffer 0
  {
    u16* dA = sAB + w * 1024;
    u16* dB = sAB + 4096 + w * 1024;
    gload16(gA, dA); gload16(gA + 16 * DIM, dA + 512);
    gload16(gB1, dB); gload16(gB2, dB + 512);
  }
  __syncthreads();
  for (int t = 0; t < 31; ++t) {
    int b = t & 1;
    {  // stage K-step t+1 into the other buffer (in flight across compute)
      int kk = (t + 1) * 32;
      u16* dA = sAB + (1 - b) * 8192 + w * 1024;
      u16* dB = sAB + (1 - b) * 8192 + 4096 + w * 1024;
      gload16(gA + kk, dA); gload16(gA + 16 * DIM + kk, dA + 512);
      gload16(gB1 + kk, dB); gload16(gB2 + kk, dB + 512);
    }
    {  // compute K-step t from buffer b
      const u16* cA = sAB + b * 8192;
      const u16* cB = sAB + b * 8192 + 4096;
      short8 a[2], bb[8];
#pragma unroll
      for (int mi = 0; mi < 2; ++mi)
        a[mi] = *(const short8*)&cA[ar + mi * 512];
#pragma unroll
      for (int ni = 0; ni < 8; ++ni)
        bb[ni] = *(const short8*)&cB[(ni * 16 + (lane & 15)) * 32 + fo];
#pragma unroll
      for (int mi = 0; mi < 2; ++mi)
#pragma unroll
        for (int ni = 0; ni < 8; ++ni)
          acc[mi][ni] = __builtin_amdgcn_mfma_f32_16x16x32_bf16(a[mi], bb[ni], acc[mi][ni], 0, 0, 0);
    }
    __syncthreads();
  }
  {  // final K-step 31 from buffer 1
    const u16* cA = sAB + 8192;
    const u16* cB = sAB + 8192 + 4096;
    short8 a[2], bb[8];
#pragma unroll
    for (int mi = 0; mi < 2; ++mi)
      a[mi] = *(const short8*)&cA[ar + mi * 512];
#pragma unroll
    for (int ni = 0; ni < 8; ++ni)
      bb[ni] = *(const short8*)&cB[(ni * 16 + (lane & 15)) * 32 + fo];
#pragma unroll
    for (int mi = 0; mi < 2; ++mi)
#pragma unroll
      for (int ni = 0; ni < 8; ++ni)
        acc[mi][ni] = __builtin_amdgcn_mfma_f32_16x16x32_bf16(a[mi], bb[ni], acc[mi][ni], 0, 0, 0);
  }

  u16* sA = sAB;
  u16* sB = sAB + 4096;
  // ---- LoRA + bias as one extra K=32 MFMA step: k0..15 = 2*xa / B, k16 = 1/bias ----
  __syncthreads();
  {
    int r = tid >> 1, kh = tid & 1;
    int sw = (r >> 1) & 3;
    int o0 = r * 32 + ((2 * kh + 0) ^ sw) * 8;
    int o1 = r * 32 + ((2 * kh + 1) ^ sw) * 8;
    u16 tmp[16];
    if (kh == 0) {
#pragma unroll
      for (int q = 0; q < 16; ++q) tmp[q] = f2bf(2.f * xagu[(size_t)(row0 + r) * 32 + q]);
    } else {
#pragma unroll
      for (int q = 0; q < 16; ++q) tmp[q] = 0;
      tmp[0] = 0x3f80;   // 1.0 at k=16
    }
    *(u16x8*)&sA[o0] = *(u16x8*)&tmp[0];
    *(u16x8*)&sA[o1] = *(u16x8*)&tmp[8];
    int f = (r < 64) ? (f0 + r) : (f0 + r - 64);
    const float* Bsrc = (r < 64) ? Bg : Bu;
    float bias = gub[e * 4096 + ((r < 64) ? f : (2048 + f))];
    if (kh == 0) {
#pragma unroll
      for (int q = 0; q < 16; ++q) tmp[q] = f2bf(Bsrc[((size_t)e * FFD + f) * 16 + q]);
    } else {
#pragma unroll
      for (int q = 0; q < 16; ++q) tmp[q] = 0;
      tmp[0] = f2bf(bias);
    }
    *(u16x8*)&sB[o0] = *(u16x8*)&tmp[0];
    *(u16x8*)&sB[o1] = *(u16x8*)&tmp[8];
  }
  __syncthreads();
  {  // gate half
    short8 a[2], b[4];
#pragma unroll
    for (int mi = 0; mi < 2; ++mi)
      a[mi] = *(const short8*)&sA[ar + mi * 512];
#pragma unroll
    for (int ni = 0; ni < 4; ++ni)
      b[ni] = *(const short8*)&sB[(ni * 16 + (lane & 15)) * 32 + fo];
#pragma unroll
    for (int mi = 0; mi < 2; ++mi)
#pragma unroll
      for (int ni = 0; ni < 4; ++ni)
        acc[mi][ni] = __builtin_amdgcn_mfma_f32_16x16x32_bf16(a[mi], b[ni], acc[mi][ni], 0, 0, 0);
  }
  __syncthreads();
  {  // swap A-lora to xa_up
    int r = tid >> 1, kh = tid & 1;
    int sw = (r >> 1) & 3;
    int o0 = r * 32 + ((2 * kh + 0) ^ sw) * 8;
    int o1 = r * 32 + ((2 * kh + 1) ^ sw) * 8;
    u16 tmp[16];
    if (kh == 0) {
#pragma unroll
      for (int q = 0; q < 16; ++q) tmp[q] = f2bf(2.f * xagu[(size_t)(row0 + r) * 32 + 16 + q]);
    } else {
#pragma unroll
      for (int q = 0; q < 16; ++q) tmp[q] = 0;
      tmp[0] = 0x3f80;
    }
    *(u16x8*)&sA[o0] = *(u16x8*)&tmp[0];
    *(u16x8*)&sA[o1] = *(u16x8*)&tmp[8];
  }
  __syncthreads();
  {  // up half
    short8 a[2], b[4];
#pragma unroll
    for (int mi = 0; mi < 2; ++mi)
      a[mi] = *(const short8*)&sA[ar + mi * 512];
#pragma unroll
    for (int ni = 0; ni < 4; ++ni)
      b[ni] = *(const short8*)&sB[((ni + 4) * 16 + (lane & 15)) * 32 + fo];
#pragma unroll
    for (int mi = 0; mi < 2; ++mi)
#pragma unroll
      for (int ni = 0; ni < 4; ++ni)
        acc[mi][ni + 4] = __builtin_amdgcn_mfma_f32_16x16x32_bf16(a[mi], b[ni], acc[mi][ni + 4], 0, 0, 0);
  }
  __syncthreads();
  // ---- register-local SwiGLU, repack through LDS for coalesced bf16 store ----
#pragma unroll
  for (int mi = 0; mi < 2; ++mi)
#pragma unroll
    for (int ni = 0; ni < 4; ++ni)
#pragma unroll
      for (int j = 0; j < 4; ++j) {
        int lr = w * 32 + mi * 16 + (lane >> 4) * 4 + j;
        int lc = ni * 16 + (lane & 15);
        float g = acc[mi][ni][j];
        float u = acc[mi][ni + 4][j];
        float s = g / (1.f + __expf(-g));
        sAB[lr * 64 + lc] = f2bf(s * u);
      }
  __syncthreads();
#pragma unroll
  for (int it = 0; it < 4; ++it) {
    int idx = it * 256 + tid;
    int rr = idx >> 3, c8 = (idx & 7) * 8;
    *(u16x8*)(act + (size_t)(row0 + rr) * FFD + f0 + c8) = *(const u16x8*)&sAB[rr * 64 + c8];
  }
}

// ------- GEMM2: down = act@Wd + b + lora; split-K=2, 2-phase pipeline -------
__global__ __launch_bounds__(256) void gemm2_k(
    const u16* __restrict__ act, const u16* __restrict__ wd_t,
    const float* __restrict__ db, const float* __restrict__ Bd,
    const float* __restrict__ aad, const int* __restrict__ offs,
    u16* __restrict__ down) {
  __shared__ __align__(16) u16 sAB[16384];
  int tid = threadIdx.x, w = tid >> 6, lane = tid & 63;
  int n0 = blockIdx.x * 128;
  int row0 = blockIdx.y * 128;
  int ks = blockIdx.z;
  size_t kbase = (size_t)ks * 1024;
  int e = 0;
  if (row0 >= offs[1]) e = 1;
  if (row0 >= offs[2]) e = 2;
  if (row0 >= offs[3]) e = 3;
  int wm = w >> 1, wn = w & 1;

  int srow = w * 32 + (lane >> 2);
  int scol = ((lane & 3) ^ ((lane >> 3) & 3)) * 8;
  const u16* gA = act + (size_t)(row0 + srow) * FFD + kbase + scol;
  const u16* gB = wd_t + (size_t)e * DIM * FFD + (size_t)(n0 + srow) * FFD + kbase + scol;
  int fo = (((lane >> 4) ^ ((lane >> 1) & 3))) * 8;
  int ar = (wm * 64 + (lane & 15)) * 32 + fo;
  int br = (wn * 64 + (lane & 15)) * 32 + fo;

  f32x4 acc[4][4];
#pragma unroll
  for (int i = 0; i < 4; ++i)
#pragma unroll
    for (int j = 0; j < 4; ++j) acc[i][j] = f32x4{0.f, 0.f, 0.f, 0.f};

  // prologue: stage K-step 0 into buffer 0
  {
    u16* dA = sAB + w * 1024;
    u16* dB = sAB + 4096 + w * 1024;
    gload16(gA, dA); gload16(gA + 16 * FFD, dA + 512);
    gload16(gB, dB); gload16(gB + 16 * FFD, dB + 512);
  }
  __syncthreads();
  for (int t = 0; t < 31; ++t) {
    int b = t & 1;
    {
      int kk = (t + 1) * 32;
      u16* dA = sAB + (1 - b) * 8192 + w * 1024;
      u16* dB = sAB + (1 - b) * 8192 + 4096 + w * 1024;
      gload16(gA + kk, dA); gload16(gA + 16 * FFD + kk, dA + 512);
      gload16(gB + kk, dB); gload16(gB + 16 * FFD + kk, dB + 512);
    }
    {
      const u16* cA = sAB + b * 8192;
      const u16* cB = sAB + b * 8192 + 4096;
      short8 a[4], bb[4];
#pragma unroll
      for (int mi = 0; mi < 4; ++mi)
        a[mi] = *(const short8*)&cA[ar + mi * 512];
#pragma unroll
      for (int ni = 0; ni < 4; ++ni)
        bb[ni] = *(const short8*)&cB[br + ni * 512];
#pragma unroll
      for (int mi = 0; mi < 4; ++mi)
#pragma unroll
        for (int ni = 0; ni < 4; ++ni)
          acc[mi][ni] = __builtin_amdgcn_mfma_f32_16x16x32_bf16(a[mi], bb[ni], acc[mi][ni], 0, 0, 0);
    }
    __syncthreads();
  }
  {  // final K-step 31 from buffer 1
    const u16* cA = sAB + 8192;
    const u16* cB = sAB + 8192 + 4096;
    short8 a[4], bb[4];
#pragma unroll
    for (int mi = 0; mi < 4; ++mi)
      a[mi] = *(const short8*)&cA[ar + mi * 512];
#pragma unroll
    for (int ni = 0; ni < 4; ++ni)
      bb[ni] = *(const short8*)&cB[br + ni * 512];
#pragma unroll
    for (int mi = 0; mi < 4; ++mi)
#pragma unroll
      for (int ni = 0; ni < 4; ++ni)
        acc[mi][ni] = __builtin_amdgcn_mfma_f32_16x16x32_bf16(a[mi], bb[ni], acc[mi][ni], 0, 0, 0);
  }

  u16* sA = sAB;
  u16* sB = sAB + 4096;
  if (ks == 0) {
    // ---- LoRA-down + bias as one extra K=32 MFMA step (half 0 only) ----
    __syncthreads();
    {
      int r = tid >> 1, kh = tid & 1;
      int sw = (r >> 1) & 3;
      int o0 = r * 32 + ((2 * kh + 0) ^ sw) * 8;
      int o1 = r * 32 + ((2 * kh + 1) ^ sw) * 8;
      u16 tmp[16];
      if (kh == 0) {
#pragma unroll
        for (int q = 0; q < 16; ++q) tmp[q] = f2bf(2.f * aad[(size_t)(row0 + r) * 16 + q]);
      } else {
#pragma unroll
        for (int q = 0; q < 16; ++q) tmp[q] = 0;
        tmp[0] = 0x3f80;
      }
      *(u16x8*)&sA[o0] = *(u16x8*)&tmp[0];
      *(u16x8*)&sA[o1] = *(u16x8*)&tmp[8];
      if (kh == 0) {
#pragma unroll
        for (int q = 0; q < 16; ++q) tmp[q] = f2bf(Bd[((size_t)e * DIM + n0 + r) * 16 + q]);
      } else {
#pragma unroll
        for (int q = 0; q < 16; ++q) tmp[q] = 0;
        tmp[0] = f2bf(db[e * DIM + n0 + r]);
      }
      *(u16x8*)&sB[o0] = *(u16x8*)&tmp[0];
      *(u16x8*)&sB[o1] = *(u16x8*)&tmp[8];
    }
    __syncthreads();
    {
      short8 a[4], b[4];
#pragma unroll
      for (int mi = 0; mi < 4; ++mi)
        a[mi] = *(const short8*)&sA[ar + mi * 512];
#pragma unroll
      for (int ni = 0; ni < 4; ++ni)
        b[ni] = *(const short8*)&sB[br + ni * 512];
#pragma unroll
      for (int mi = 0; mi < 4; ++mi)
#pragma unroll
        for (int ni = 0; ni < 4; ++ni)
          acc[mi][ni] = __builtin_amdgcn_mfma_f32_16x16x32_bf16(a[mi], b[ni], acc[mi][ni], 0, 0, 0);
    }
  }
  // ---- store bf16 partial ----
#pragma unroll
  for (int mi = 0; mi < 4; ++mi)
#pragma unroll
    for (int ni = 0; ni < 4; ++ni)
#pragma unroll
      for (int j = 0; j < 4; ++j) {
        int lr = wm * 64 + mi * 16 + (lane >> 4) * 4 + j;
        int lc = wn * 64 + ni * 16 + (lane & 15);
        down[((size_t)ks * NRP + row0 + lr) * DIM + n0 + lc] = f2bf(acc[mi][ni][j]);
      }
}

// ---------------- weighted combine (sums split-K halves) --------------------
__global__ void combine_k(const u16* __restrict__ down, const int* __restrict__ pairrow,
                          const float* __restrict__ selw, float* __restrict__ out) {
  int t = blockIdx.x, tid = threadIdx.x;   // 256 threads, 4 cols each
  int r0 = pairrow[2 * t], r1 = pairrow[2 * t + 1];
  float w0 = selw[2 * t], w1 = selw[2 * t + 1];
  u16x4 a0 = *(const u16x4*)(down + ((size_t)r0) * DIM + tid * 4);
  u16x4 a1 = *(const u16x4*)(down + ((size_t)NRP + r0) * DIM + tid * 4);
  u16x4 b0 = *(const u16x4*)(down + ((size_t)r1) * DIM + tid * 4);
  u16x4 b1 = *(const u16x4*)(down + ((size_t)NRP + r1) * DIM + tid * 4);
  f32x4 o;
#pragma unroll
  for (int j = 0; j < 4; ++j)
    o[j] = w0 * (bf2f(a0[j]) + bf2f(a1[j])) + w1 * (bf2f(b0[j]) + bf2f(b1[j]));
  *(f32x4*)(out + (size_t)t * DIM + tid * 4) = o;
}

extern "C" void kernel_launch(void* const* d_in, const int* in_sizes, int n_in,
                              void* d_out, int out_size, void* d_ws, size_t ws_size,
                              hipStream_t stream) {
  const float* x         = (const float*)d_in[0];
  const float* gate_w    = (const float*)d_in[1];
  const float* gate_up_w = (const float*)d_in[2];
  const float* gate_up_b = (const float*)d_in[3];
  const float* down_w    = (const float*)d_in[4];
  const float* down_b    = (const float*)d_in[5];
  const float* A_gate    = (const float*)d_in[6];
  const float* B_gate    = (const float*)d_in[7];
  const float* A_up      = (const float*)d_in[8];
  const float* B_up      = (const float*)d_in[9];
  const float* A_down    = (const float*)d_in[10];
  const float* B_down    = (const float*)d_in[11];

  float* out_final  = (float*)d_out;
  float* out_logits = out_final + (size_t)T_TOK * DIM;

  char* ws = (char*)d_ws;
  size_t o = 0;
  auto take = [&](size_t bytes) -> void* {
    void* p = ws + o;
    o = (o + bytes + 255) & ~(size_t)255;
    return p;
  };
  int*   offs    = (int*)take(64);
  int*   sel     = (int*)take((size_t)T_TOK * 2 * 4);
  float* selw    = (float*)take((size_t)T_TOK * 2 * 4);
  int*   pos     = (int*)take((size_t)T_TOK * 2 * 4);
  int*   pairrow = (int*)take((size_t)T_TOK * 2 * 4);
  int*   rowtok  = (int*)take((size_t)NRP * 4);
  float* xagu    = (float*)take((size_t)NRP * 32 * 4);
  float* aadb    = (float*)take((size_t)NRP * 16 * 4);
  u16*   abgu    = (u16*)take((size_t)NEXP * 32 * DIM * 2);
  u16*   adb     = (u16*)take((size_t)NEXP * 16 * FFD * 2);
  u16*   xg      = (u16*)take((size_t)NRP * DIM * 2);
  u16*   actb    = (u16*)take((size_t)NRP * FFD * 2);
  u16*   downb   = (u16*)take((size_t)2 * NRP * DIM * 2);
  u16*   wgu_t   = (u16*)take((size_t)NEXP * 2 * FFD * DIM * 2);
  u16*   wd_t    = (u16*)take((size_t)NEXP * DIM * FFD * 2);
  (void)ws_size; (void)in_sizes; (void)n_in; (void)out_size;

  // weight transposes (fp32 [K][N] -> bf16 [N][K]) — independent of routing
  transpose_k<<<dim3(128, 32, NEXP), dim3(32, 8), 0, stream>>>(gate_up_w, wgu_t, DIM, 2 * FFD);
  transpose_k<<<dim3(32, 64, NEXP), dim3(32, 8), 0, stream>>>(down_w, wd_t, FFD, DIM);
  cvtA_k<<<256, 256, 0, stream>>>(A_gate, A_up, A_down, abgu, adb);

  router_k<<<T_TOK, 64, 0, stream>>>(x, gate_w, out_logits, sel, selw);
  scan_k<<<1, 1024, 0, stream>>>(sel, pos, offs, rowtok, pairrow);
  gather_k<<<NRP, 256, 0, stream>>>(x, rowtok, xg);
  xa_k<<<NRP / 2, 64, 0, stream>>>(xg, abgu, offs, xagu);
  gemm1_k<<<dim3(32, MTILES), 256, 0, stream>>>(xg, wgu_t, gate_up_b, B_gate, B_up,
                                                xagu, offs, actb);
  aad_k<<<NRP / 2, 64, 0, stream>>>(actb, adb, offs, aadb);
  gemm2_k<<<dim3(8, MTILES, 2), 256, 0, stream>>>(actb, wd_t, down_b, B_down, aadb, offs, downb);
  combine_k<<<T_TOK, 256, 0, stream>>>(downb, pairrow, selw, out_final);
}

// Round 5
// 272.426 us; speedup vs baseline: 1.3712x; 1.0635x over previous
//
#include <hip/hip_runtime.h>

#define T_TOK 4096
#define DIM   1024
#define FFD   2048
#define NEXP  4
#define NRP   8704      // 68*128 padded row capacity
#define MTILES 68

typedef unsigned short u16;
typedef __attribute__((ext_vector_type(8))) short short8;
typedef __attribute__((ext_vector_type(4))) float f32x4;
typedef __attribute__((ext_vector_type(8))) unsigned short u16x8;
typedef __attribute__((ext_vector_type(4))) unsigned short u16x4;

typedef __attribute__((address_space(1))) unsigned int as1_u32;
typedef __attribute__((address_space(3))) unsigned int as3_u32;

__device__ __forceinline__ u16 f2bf(float f) {
  union { float f; unsigned u; } v; v.f = f;
  unsigned u = v.u;
  return (u16)((u + 0x7fffu + ((u >> 16) & 1u)) >> 16);   // RNE
}
__device__ __forceinline__ float bf2f(u16 h) {
  union { unsigned u; float f; } v; v.u = ((unsigned)h) << 16;
  return v.f;
}
__device__ __forceinline__ void gload16(const void* g, void* l) {
  __builtin_amdgcn_global_load_lds((const as1_u32*)g, (as3_u32*)l, 16, 0, 0);
}

// ---------------- router: fp32 logits, softmax top-2, renorm ----------------
__global__ void router_k(const float* __restrict__ x, const float* __restrict__ gw,
                         float* __restrict__ logits_out, int* __restrict__ sel,
                         float* __restrict__ selw) {
  int t = blockIdx.x;
  int lane = threadIdx.x;           // block = 64 (one wave)
  float xv[16];
#pragma unroll
  for (int i = 0; i < 16; ++i) xv[i] = x[(size_t)t * DIM + lane + i * 64];
  float l[4];
#pragma unroll
  for (int e = 0; e < 4; ++e) {
    float s = 0.f;
#pragma unroll
    for (int i = 0; i < 16; ++i) s += xv[i] * gw[e * DIM + lane + i * 64];
#pragma unroll
    for (int off = 32; off > 0; off >>= 1) s += __shfl_xor(s, off, 64);
    l[e] = s;
  }
  if (lane == 0) {
#pragma unroll
    for (int e = 0; e < 4; ++e) logits_out[(size_t)t * 4 + e] = l[e];
    int e0 = 0; float b0 = l[0];
    for (int e = 1; e < 4; ++e) if (l[e] > b0) { b0 = l[e]; e0 = e; }
    int e1 = -1; float b1 = -3.4e38f;
    for (int e = 0; e < 4; ++e) if (e != e0 && l[e] > b1) { b1 = l[e]; e1 = e; }
    float p1 = expf(b1 - b0);
    float w0 = 1.f / (1.f + p1);
    sel[2 * t] = e0; sel[2 * t + 1] = e1;
    selw[2 * t] = w0; selw[2 * t + 1] = 1.f - w0;
  }
}

// ------------- deterministic bucket assignment (single block) ---------------
__global__ void scan_k(const int* __restrict__ sel, int* __restrict__ pos,
                       int* __restrict__ offs, int* __restrict__ rowtok,
                       int* __restrict__ pairrow) {
  __shared__ int base[4];
  __shared__ int wsum[16][4];
  __shared__ int off_s[5];
  int tid = threadIdx.x, lane = tid & 63, wid = tid >> 6;   // 1024 threads = 16 waves
  if (tid < 4) base[tid] = 0;
  __syncthreads();
  for (int chunk = 0; chunk < 4; ++chunk) {
    int t = chunk * 1024 + tid;
    int e0 = sel[2 * t], e1 = sel[2 * t + 1];
    unsigned long long ltm = (1ull << lane) - 1ull;
    bool f[4]; int within[4];
#pragma unroll
    for (int e = 0; e < 4; ++e) {
      f[e] = (e0 == e) || (e1 == e);
      unsigned long long m = __ballot(f[e]);
      within[e] = __popcll(m & ltm);
      if (lane == 0) wsum[wid][e] = __popcll(m);
    }
    __syncthreads();
    int wbase[4] = {0, 0, 0, 0}, tot[4] = {0, 0, 0, 0};
    for (int i = 0; i < 16; ++i)
#pragma unroll
      for (int e = 0; e < 4; ++e) {
        int v = wsum[i][e];
        if (i < wid) wbase[e] += v;
        tot[e] += v;
      }
#pragma unroll
    for (int e = 0; e < 4; ++e)
      if (f[e]) {
        int p = base[e] + wbase[e] + within[e];
        if (e0 == e) pos[2 * t] = p; else pos[2 * t + 1] = p;
      }
    __syncthreads();
    if (tid < 4) base[tid] += tot[tid];
    __syncthreads();
  }
  if (tid == 0) {
    int o = 0;
    for (int e = 0; e < 4; ++e) { off_s[e] = o; o += ((base[e] + 127) >> 7) << 7; }
    off_s[4] = o;
    for (int i = 0; i < 5; ++i) offs[i] = off_s[i];
  }
  __syncthreads();
  for (int r = tid; r < NRP; r += 1024) rowtok[r] = -1;
  __syncthreads();
  for (int t = tid; t < T_TOK; t += 1024) {
#pragma unroll
    for (int s = 0; s < 2; ++s) {
      int e = sel[2 * t + s];
      int rr = off_s[e] + pos[2 * t + s];
      pairrow[2 * t + s] = rr;
      rowtok[rr] = t;
    }
  }
}

// ---------------- gather x rows (bucket order) -> bf16 ----------------------
__global__ void gather_k(const float* __restrict__ x, const int* __restrict__ rowtok,
                         u16* __restrict__ xg) {
  int r = blockIdx.x, tid = threadIdx.x;   // 256 threads, 4 floats each
  int t = rowtok[r];
  float4 v = make_float4(0.f, 0.f, 0.f, 0.f);
  if (t >= 0) v = ((const float4*)(x + (size_t)t * DIM))[tid];
  u16x4 o;
  o[0] = f2bf(v.x); o[1] = f2bf(v.y); o[2] = f2bf(v.z); o[3] = f2bf(v.w);
  ((u16x4*)(xg + (size_t)r * DIM))[tid] = o;
}

// -------- pre-convert LoRA A matrices to bf16 (abgu[4][32][1024], adb[4][16][2048])
__global__ void cvtA_k(const float* __restrict__ Ag, const float* __restrict__ Au,
                       const float* __restrict__ Ad, u16* __restrict__ abgu,
                       u16* __restrict__ adb) {
  int g = blockIdx.x * 256 + threadIdx.x;   // each handles 4 elements
  if (g < 32768) {
    int flat = g * 4;
    int e = flat >> 15;
    int rem = flat & 32767;
    int q = rem >> 10;
    int d = rem & 1023;
    const float* src = (q < 16) ? (Ag + ((size_t)e * 16 + q) * DIM + d)
                                : (Au + ((size_t)e * 16 + (q - 16)) * DIM + d);
    float4 v = *(const float4*)src;
    u16x4 o; o[0] = f2bf(v.x); o[1] = f2bf(v.y); o[2] = f2bf(v.z); o[3] = f2bf(v.w);
    *(u16x4*)(abgu + (size_t)flat) = o;
  } else {
    int flat = (g - 32768) * 4;
    float4 v = *(const float4*)(Ad + flat);
    u16x4 o; o[0] = f2bf(v.x); o[1] = f2bf(v.y); o[2] = f2bf(v.z); o[3] = f2bf(v.w);
    *(u16x4*)(adb + (size_t)flat) = o;
  }
}

// ---------------- per-row LoRA A-projections, 2 rows per wave ----------------
__global__ void xa_k(const u16* __restrict__ xg, const u16* __restrict__ abgu,
                     const int* __restrict__ offs, float* __restrict__ xagu) {
  int r0 = blockIdx.x * 2, lane = threadIdx.x;   // block = 64
  int e = 0;
  if (r0 >= offs[1]) e = 1;
  if (r0 >= offs[2]) e = 2;
  if (r0 >= offs[3]) e = 3;
  float x0[16], x1[16];
#pragma unroll
  for (int i = 0; i < 4; ++i) {
    u16x4 v0 = ((const u16x4*)(xg + (size_t)r0 * DIM))[lane + i * 64];
    u16x4 v1 = ((const u16x4*)(xg + (size_t)(r0 + 1) * DIM))[lane + i * 64];
#pragma unroll
    for (int j = 0; j < 4; ++j) { x0[i * 4 + j] = bf2f(v0[j]); x1[i * 4 + j] = bf2f(v1[j]); }
  }
  const u16* A = abgu + (size_t)e * 32 * DIM;
  for (int q = 0; q < 32; ++q) {
    float s0 = 0.f, s1 = 0.f;
#pragma unroll
    for (int i = 0; i < 4; ++i) {
      u16x4 av = ((const u16x4*)(A + (size_t)q * DIM))[lane + i * 64];
#pragma unroll
      for (int j = 0; j < 4; ++j) {
        float a = bf2f(av[j]);
        s0 += x0[i * 4 + j] * a; s1 += x1[i * 4 + j] * a;
      }
    }
#pragma unroll
    for (int off = 32; off > 0; off >>= 1) { s0 += __shfl_xor(s0, off, 64); s1 += __shfl_xor(s1, off, 64); }
    if (lane == 0) { xagu[(size_t)r0 * 32 + q] = s0; xagu[(size_t)(r0 + 1) * 32 + q] = s1; }
  }
}

__global__ void aad_k(const u16* __restrict__ act, const u16* __restrict__ adb,
                      const int* __restrict__ offs, float* __restrict__ aad) {
  int r0 = blockIdx.x * 2, lane = threadIdx.x;
  int e = 0;
  if (r0 >= offs[1]) e = 1;
  if (r0 >= offs[2]) e = 2;
  if (r0 >= offs[3]) e = 3;
  float x0[32], x1[32];
#pragma unroll
  for (int i = 0; i < 8; ++i) {
    u16x4 v0 = ((const u16x4*)(act + (size_t)r0 * FFD))[lane + i * 64];
    u16x4 v1 = ((const u16x4*)(act + (size_t)(r0 + 1) * FFD))[lane + i * 64];
#pragma unroll
    for (int j = 0; j < 4; ++j) { x0[i * 4 + j] = bf2f(v0[j]); x1[i * 4 + j] = bf2f(v1[j]); }
  }
  const u16* A = adb + (size_t)e * 16 * FFD;
  for (int q = 0; q < 16; ++q) {
    float s0 = 0.f, s1 = 0.f;
#pragma unroll
    for (int i = 0; i < 8; ++i) {
      u16x4 av = ((const u16x4*)(A + (size_t)q * FFD))[lane + i * 64];
#pragma unroll
      for (int j = 0; j < 4; ++j) {
        float a = bf2f(av[j]);
        s0 += x0[i * 4 + j] * a; s1 += x1[i * 4 + j] * a;
      }
    }
#pragma unroll
    for (int off = 32; off > 0; off >>= 1) { s0 += __shfl_xor(s0, off, 64); s1 += __shfl_xor(s1, off, 64); }
    if (lane == 0) { aad[(size_t)r0 * 16 + q] = s0; aad[(size_t)(r0 + 1) * 16 + q] = s1; }
  }
}

// ---------------- weight transpose fp32[K][N] -> bf16[N][K] ------------------
__global__ void transpose_k(const float* __restrict__ in, u16* __restrict__ out,
                            int K, int N) {
  int e = blockIdx.z;
  int n0 = blockIdx.x * 32, k0 = blockIdx.y * 32;
  const float* I = in + (size_t)e * K * N;
  u16* O = out + (size_t)e * N * K;
  __shared__ u16 tile[32][33];
#pragma unroll
  for (int i = 0; i < 4; ++i) {
    int k = k0 + threadIdx.y + i * 8;
    tile[threadIdx.y + i * 8][threadIdx.x] = f2bf(I[(size_t)k * N + n0 + threadIdx.x]);
  }
  __syncthreads();
#pragma unroll
  for (int i = 0; i < 4; ++i) {
    int n = n0 + threadIdx.y + i * 8;
    O[(size_t)n * K + k0 + threadIdx.x] = tile[threadIdx.x][threadIdx.y + i * 8];
  }
}

// ---------------- GEMM1: act = swiglu(x@Wgu + b + lora) ---------------------
// Triple-buffered LDS (48KB), depth-2 prefetch, counted s_waitcnt vmcnt(4)
// before a raw s_barrier (batch t+1 stays in flight across the barrier).
// Fully unrolled K-loop: all global/LDS offsets fold into instruction
// immediates (kills per-step address VALU). T2 swizzle kept.
__global__ __launch_bounds__(256) void gemm1_k(
    const u16* __restrict__ xg, const u16* __restrict__ wgu_t,
    const float* __restrict__ gub, const float* __restrict__ Bg,
    const float* __restrict__ Bu, const float* __restrict__ xagu,
    const int* __restrict__ offs, u16* __restrict__ act) {
  __shared__ __align__(16) u16 sAB[24576];   // 3 bufs x (A 4096 + B 4096) u16
  int tid = threadIdx.x, w = tid >> 6, lane = tid & 63;
  int f0 = blockIdx.x * 64;
  int row0 = blockIdx.y * 128;
  int e = 0;
  if (row0 >= offs[1]) e = 1;
  if (row0 >= offs[2]) e = 2;
  if (row0 >= offs[3]) e = 3;

  int srow = w * 32 + (lane >> 2);
  int scol = ((lane & 3) ^ ((lane >> 3) & 3)) * 8;     // pre-swizzled global source (T2)
  const u16* gA = xg + (size_t)(row0 + srow) * DIM + scol;
  const u16* gA2 = gA + 16 * DIM;
  int n1 = srow, n2 = srow + 16;
  int gr1 = (n1 < 64) ? (f0 + n1) : (2048 + f0 + n1 - 64);
  int gr2 = (n2 < 64) ? (f0 + n2) : (2048 + f0 + n2 - 64);
  const u16* gB1 = wgu_t + ((size_t)e << 22) + (size_t)gr1 * DIM + scol;
  const u16* gB2 = wgu_t + ((size_t)e << 22) + (size_t)gr2 * DIM + scol;
  int fo = (((lane >> 4) ^ ((lane >> 1) & 3))) * 8;    // swizzled fragment k-offset
  int ar = (w * 32 + (lane & 15)) * 32 + fo;           // A-frag base (row stride 32)

  f32x4 acc[2][8];
#pragma unroll
  for (int i = 0; i < 2; ++i)
#pragma unroll
    for (int j = 0; j < 8; ++j) acc[i][j] = f32x4{0.f, 0.f, 0.f, 0.f};

  // prologue: batch 0 -> buf0, batch 1 -> buf1
  {
    u16* d0 = sAB + w * 1024;
    gload16(gA, d0); gload16(gA2, d0 + 512);
    gload16(gB1, d0 + 4096); gload16(gB2, d0 + 4608);
    u16* d1 = sAB + 8192 + w * 1024;
    gload16(gA + 32, d1); gload16(gA2 + 32, d1 + 512);
    gload16(gB1 + 32, d1 + 4096); gload16(gB2 + 32, d1 + 4608);
  }
#pragma unroll
  for (int t = 0; t < 32; ++t) {
    if (t == 31) asm volatile("s_waitcnt vmcnt(0)\n\ts_barrier" ::: "memory");
    else         asm volatile("s_waitcnt vmcnt(4)\n\ts_barrier" ::: "memory");
    if (t < 30) {
      int kk = (t + 2) * 32;
      u16* dA = sAB + ((t + 2) % 3) * 8192 + w * 1024;
      gload16(gA + kk, dA); gload16(gA2 + kk, dA + 512);
      gload16(gB1 + kk, dA + 4096); gload16(gB2 + kk, dA + 4608);
    }
    const u16* cA = sAB + (t % 3) * 8192;
    const u16* cB = cA + 4096;
    short8 a[2], bb[8];
#pragma unroll
    for (int mi = 0; mi < 2; ++mi)
      a[mi] = *(const short8*)&cA[ar + mi * 512];
#pragma unroll
    for (int ni = 0; ni < 8; ++ni)
      bb[ni] = *(const short8*)&cB[(ni * 16 + (lane & 15)) * 32 + fo];
#pragma unroll
    for (int mi = 0; mi < 2; ++mi)
#pragma unroll
      for (int ni = 0; ni < 8; ++ni)
        acc[mi][ni] = __builtin_amdgcn_mfma_f32_16x16x32_bf16(a[mi], bb[ni], acc[mi][ni], 0, 0, 0);
  }

  u16* sA = sAB;
  u16* sB = sAB + 4096;
  // ---- LoRA + bias as one extra K=32 MFMA step: k0..15 = 2*xa / B, k16 = 1/bias ----
  __syncthreads();
  {
    int r = tid >> 1, kh = tid & 1;
    int sw = (r >> 1) & 3;
    int o0 = r * 32 + ((2 * kh + 0) ^ sw) * 8;
    int o1 = r * 32 + ((2 * kh + 1) ^ sw) * 8;
    u16 tmp[16];
    if (kh == 0) {
#pragma unroll
      for (int q = 0; q < 16; ++q) tmp[q] = f2bf(2.f * xagu[(size_t)(row0 + r) * 32 + q]);
    } else {
#pragma unroll
      for (int q = 0; q < 16; ++q) tmp[q] = 0;
      tmp[0] = 0x3f80;   // 1.0 at k=16
    }
    *(u16x8*)&sA[o0] = *(u16x8*)&tmp[0];
    *(u16x8*)&sA[o1] = *(u16x8*)&tmp[8];
    int f = (r < 64) ? (f0 + r) : (f0 + r - 64);
    const float* Bsrc = (r < 64) ? Bg : Bu;
    float bias = gub[e * 4096 + ((r < 64) ? f : (2048 + f))];
    if (kh == 0) {
#pragma unroll
      for (int q = 0; q < 16; ++q) tmp[q] = f2bf(Bsrc[((size_t)e * FFD + f) * 16 + q]);
    } else {
#pragma unroll
      for (int q = 0; q < 16; ++q) tmp[q] = 0;
      tmp[0] = f2bf(bias);
    }
    *(u16x8*)&sB[o0] = *(u16x8*)&tmp[0];
    *(u16x8*)&sB[o1] = *(u16x8*)&tmp[8];
  }
  __syncthreads();
  {  // gate half
    short8 a[2], b[4];
#pragma unroll
    for (int mi = 0; mi < 2; ++mi)
      a[mi] = *(const short8*)&sA[ar + mi * 512];
#pragma unroll
    for (int ni = 0; ni < 4; ++ni)
      b[ni] = *(const short8*)&sB[(ni * 16 + (lane & 15)) * 32 + fo];
#pragma unroll
    for (int mi = 0; mi < 2; ++mi)
#pragma unroll
      for (int ni = 0; ni < 4; ++ni)
        acc[mi][ni] = __builtin_amdgcn_mfma_f32_16x16x32_bf16(a[mi], b[ni], acc[mi][ni], 0, 0, 0);
  }
  __syncthreads();
  {  // swap A-lora to xa_up
    int r = tid >> 1, kh = tid & 1;
    int sw = (r >> 1) & 3;
    int o0 = r * 32 + ((2 * kh + 0) ^ sw) * 8;
    int o1 = r * 32 + ((2 * kh + 1) ^ sw) * 8;
    u16 tmp[16];
    if (kh == 0) {
#pragma unroll
      for (int q = 0; q < 16; ++q) tmp[q] = f2bf(2.f * xagu[(size_t)(row0 + r) * 32 + 16 + q]);
    } else {
#pragma unroll
      for (int q = 0; q < 16; ++q) tmp[q] = 0;
      tmp[0] = 0x3f80;
    }
    *(u16x8*)&sA[o0] = *(u16x8*)&tmp[0];
    *(u16x8*)&sA[o1] = *(u16x8*)&tmp[8];
  }
  __syncthreads();
  {  // up half
    short8 a[2], b[4];
#pragma unroll
    for (int mi = 0; mi < 2; ++mi)
      a[mi] = *(const short8*)&sA[ar + mi * 512];
#pragma unroll
    for (int ni = 0; ni < 4; ++ni)
      b[ni] = *(const short8*)&sB[((ni + 4) * 16 + (lane & 15)) * 32 + fo];
#pragma unroll
    for (int mi = 0; mi < 2; ++mi)
#pragma unroll
      for (int ni = 0; ni < 4; ++ni)
        acc[mi][ni + 4] = __builtin_amdgcn_mfma_f32_16x16x32_bf16(a[mi], b[ni], acc[mi][ni + 4], 0, 0, 0);
  }
  __syncthreads();
  // ---- register-local SwiGLU, repack through LDS for coalesced bf16 store ----
#pragma unroll
  for (int mi = 0; mi < 2; ++mi)
#pragma unroll
    for (int ni = 0; ni < 4; ++ni)
#pragma unroll
      for (int j = 0; j < 4; ++j) {
        int lr = w * 32 + mi * 16 + (lane >> 4) * 4 + j;
        int lc = ni * 16 + (lane & 15);
        float g = acc[mi][ni][j];
        float u = acc[mi][ni + 4][j];
        float s = g / (1.f + __expf(-g));
        sAB[lr * 64 + lc] = f2bf(s * u);
      }
  __syncthreads();
#pragma unroll
  for (int it = 0; it < 4; ++it) {
    int idx = it * 256 + tid;
    int rr = idx >> 3, c8 = (idx & 7) * 8;
    *(u16x8*)(act + (size_t)(row0 + rr) * FFD + f0 + c8) = *(const u16x8*)&sAB[rr * 64 + c8];
  }
}

// ------- GEMM2: down = act@Wd + b + lora; split-K=2, counted-vmcnt pipeline --
__global__ __launch_bounds__(256) void gemm2_k(
    const u16* __restrict__ act, const u16* __restrict__ wd_t,
    const float* __restrict__ db, const float* __restrict__ Bd,
    const float* __restrict__ aad, const int* __restrict__ offs,
    u16* __restrict__ down) {
  __shared__ __align__(16) u16 sAB[24576];
  int tid = threadIdx.x, w = tid >> 6, lane = tid & 63;
  int n0 = blockIdx.x * 128;
  int row0 = blockIdx.y * 128;
  int ks = blockIdx.z;
  size_t kbase = (size_t)ks * 1024;
  int e = 0;
  if (row0 >= offs[1]) e = 1;
  if (row0 >= offs[2]) e = 2;
  if (row0 >= offs[3]) e = 3;
  int wm = w >> 1, wn = w & 1;

  int srow = w * 32 + (lane >> 2);
  int scol = ((lane & 3) ^ ((lane >> 3) & 3)) * 8;
  const u16* gA = act + (size_t)(row0 + srow) * FFD + kbase + scol;
  const u16* gA2 = gA + 16 * FFD;
  const u16* gB = wd_t + (size_t)e * DIM * FFD + (size_t)(n0 + srow) * FFD + kbase + scol;
  const u16* gB2 = gB + 16 * FFD;
  int fo = (((lane >> 4) ^ ((lane >> 1) & 3))) * 8;
  int ar = (wm * 64 + (lane & 15)) * 32 + fo;
  int br = (wn * 64 + (lane & 15)) * 32 + fo;

  f32x4 acc[4][4];
#pragma unroll
  for (int i = 0; i < 4; ++i)
#pragma unroll
    for (int j = 0; j < 4; ++j) acc[i][j] = f32x4{0.f, 0.f, 0.f, 0.f};

  // prologue: batch 0 -> buf0, batch 1 -> buf1
  {
    u16* d0 = sAB + w * 1024;
    gload16(gA, d0); gload16(gA2, d0 + 512);
    gload16(gB, d0 + 4096); gload16(gB2, d0 + 4608);
    u16* d1 = sAB + 8192 + w * 1024;
    gload16(gA + 32, d1); gload16(gA2 + 32, d1 + 512);
    gload16(gB + 32, d1 + 4096); gload16(gB2 + 32, d1 + 4608);
  }
#pragma unroll
  for (int t = 0; t < 32; ++t) {
    if (t == 31) asm volatile("s_waitcnt vmcnt(0)\n\ts_barrier" ::: "memory");
    else         asm volatile("s_waitcnt vmcnt(4)\n\ts_barrier" ::: "memory");
    if (t < 30) {
      int kk = (t + 2) * 32;
      u16* dA = sAB + ((t + 2) % 3) * 8192 + w * 1024;
      gload16(gA + kk, dA); gload16(gA2 + kk, dA + 512);
      gload16(gB + kk, dA + 4096); gload16(gB2 + kk, dA + 4608);
    }
    const u16* cA = sAB + (t % 3) * 8192;
    const u16* cB = cA + 4096;
    short8 a[4], bb[4];
#pragma unroll
    for (int mi = 0; mi < 4; ++mi)
      a[mi] = *(const short8*)&cA[ar + mi * 512];
#pragma unroll
    for (int ni = 0; ni < 4; ++ni)
      bb[ni] = *(const short8*)&cB[br + ni * 512];
#pragma unroll
    for (int mi = 0; mi < 4; ++mi)
#pragma unroll
      for (int ni = 0; ni < 4; ++ni)
        acc[mi][ni] = __builtin_amdgcn_mfma_f32_16x16x32_bf16(a[mi], bb[ni], acc[mi][ni], 0, 0, 0);
  }

  u16* sA = sAB;
  u16* sB = sAB + 4096;
  if (ks == 0) {
    // ---- LoRA-down + bias as one extra K=32 MFMA step (half 0 only) ----
    __syncthreads();
    {
      int r = tid >> 1, kh = tid & 1;
      int sw = (r >> 1) & 3;
      int o0 = r * 32 + ((2 * kh + 0) ^ sw) * 8;
      int o1 = r * 32 + ((2 * kh + 1) ^ sw) * 8;
      u16 tmp[16];
      if (kh == 0) {
#pragma unroll
        for (int q = 0; q < 16; ++q) tmp[q] = f2bf(2.f * aad[(size_t)(row0 + r) * 16 + q]);
      } else {
#pragma unroll
        for (int q = 0; q < 16; ++q) tmp[q] = 0;
        tmp[0] = 0x3f80;
      }
      *(u16x8*)&sA[o0] = *(u16x8*)&tmp[0];
      *(u16x8*)&sA[o1] = *(u16x8*)&tmp[8];
      if (kh == 0) {
#pragma unroll
        for (int q = 0; q < 16; ++q) tmp[q] = f2bf(Bd[((size_t)e * DIM + n0 + r) * 16 + q]);
      } else {
#pragma unroll
        for (int q = 0; q < 16; ++q) tmp[q] = 0;
        tmp[0] = f2bf(db[e * DIM + n0 + r]);
      }
      *(u16x8*)&sB[o0] = *(u16x8*)&tmp[0];
      *(u16x8*)&sB[o1] = *(u16x8*)&tmp[8];
    }
    __syncthreads();
    {
      short8 a[4], b[4];
#pragma unroll
      for (int mi = 0; mi < 4; ++mi)
        a[mi] = *(const short8*)&sA[ar + mi * 512];
#pragma unroll
      for (int ni = 0; ni < 4; ++ni)
        b[ni] = *(const short8*)&sB[br + ni * 512];
#pragma unroll
      for (int mi = 0; mi < 4; ++mi)
#pragma unroll
        for (int ni = 0; ni < 4; ++ni)
          acc[mi][ni] = __builtin_amdgcn_mfma_f32_16x16x32_bf16(a[mi], b[ni], acc[mi][ni], 0, 0, 0);
    }
  }
  // ---- store bf16 partial ----
#pragma unroll
  for (int mi = 0; mi < 4; ++mi)
#pragma unroll
    for (int ni = 0; ni < 4; ++ni)
#pragma unroll
      for (int j = 0; j < 4; ++j) {
        int lr = wm * 64 + mi * 16 + (lane >> 4) * 4 + j;
        int lc = wn * 64 + ni * 16 + (lane & 15);
        down[((size_t)ks * NRP + row0 + lr) * DIM + n0 + lc] = f2bf(acc[mi][ni][j]);
      }
}

// ---------------- weighted combine (sums split-K halves) --------------------
__global__ void combine_k(const u16* __restrict__ down, const int* __restrict__ pairrow,
                          const float* __restrict__ selw, float* __restrict__ out) {
  int t = blockIdx.x, tid = threadIdx.x;   // 256 threads, 4 cols each
  int r0 = pairrow[2 * t], r1 = pairrow[2 * t + 1];
  float w0 = selw[2 * t], w1 = selw[2 * t + 1];
  u16x4 a0 = *(const u16x4*)(down + ((size_t)r0) * DIM + tid * 4);
  u16x4 a1 = *(const u16x4*)(down + ((size_t)NRP + r0) * DIM + tid * 4);
  u16x4 b0 = *(const u16x4*)(down + ((size_t)r1) * DIM + tid * 4);
  u16x4 b1 = *(const u16x4*)(down + ((size_t)NRP + r1) * DIM + tid * 4);
  f32x4 o;
#pragma unroll
  for (int j = 0; j < 4; ++j)
    o[j] = w0 * (bf2f(a0[j]) + bf2f(a1[j])) + w1 * (bf2f(b0[j]) + bf2f(b1[j]));
  *(f32x4*)(out + (size_t)t * DIM + tid * 4) = o;
}

extern "C" void kernel_launch(void* const* d_in, const int* in_sizes, int n_in,
                              void* d_out, int out_size, void* d_ws, size_t ws_size,
                              hipStream_t stream) {
  const float* x         = (const float*)d_in[0];
  const float* gate_w    = (const float*)d_in[1];
  const float* gate_up_w = (const float*)d_in[2];
  const float* gate_up_b = (const float*)d_in[3];
  const float* down_w    = (const float*)d_in[4];
  const float* down_b    = (const float*)d_in[5];
  const float* A_gate    = (const float*)d_in[6];
  const float* B_gate    = (const float*)d_in[7];
  const float* A_up      = (const float*)d_in[8];
  const float* B_up      = (const float*)d_in[9];
  const float* A_down    = (const float*)d_in[10];
  const float* B_down    = (const float*)d_in[11];

  float* out_final  = (float*)d_out;
  float* out_logits = out_final + (size_t)T_TOK * DIM;

  char* ws = (char*)d_ws;
  size_t o = 0;
  auto take = [&](size_t bytes) -> void* {
    void* p = ws + o;
    o = (o + bytes + 255) & ~(size_t)255;
    return p;
  };
  int*   offs    = (int*)take(64);
  int*   sel     = (int*)take((size_t)T_TOK * 2 * 4);
  float* selw    = (float*)take((size_t)T_TOK * 2 * 4);
  int*   pos     = (int*)take((size_t)T_TOK * 2 * 4);
  int*   pairrow = (int*)take((size_t)T_TOK * 2 * 4);
  int*   rowtok  = (int*)take((size_t)NRP * 4);
  float* xagu    = (float*)take((size_t)NRP * 32 * 4);
  float* aadb    = (float*)take((size_t)NRP * 16 * 4);
  u16*   abgu    = (u16*)take((size_t)NEXP * 32 * DIM * 2);
  u16*   adb     = (u16*)take((size_t)NEXP * 16 * FFD * 2);
  u16*   xg      = (u16*)take((size_t)NRP * DIM * 2);
  u16*   actb    = (u16*)take((size_t)NRP * FFD * 2);
  u16*   downb   = (u16*)take((size_t)2 * NRP * DIM * 2);
  u16*   wgu_t   = (u16*)take((size_t)NEXP * 2 * FFD * DIM * 2);
  u16*   wd_t    = (u16*)take((size_t)NEXP * DIM * FFD * 2);
  (void)ws_size; (void)in_sizes; (void)n_in; (void)out_size;

  // weight transposes (fp32 [K][N] -> bf16 [N][K]) — independent of routing
  transpose_k<<<dim3(128, 32, NEXP), dim3(32, 8), 0, stream>>>(gate_up_w, wgu_t, DIM, 2 * FFD);
  transpose_k<<<dim3(32, 64, NEXP), dim3(32, 8), 0, stream>>>(down_w, wd_t, FFD, DIM);
  cvtA_k<<<256, 256, 0, stream>>>(A_gate, A_up, A_down, abgu, adb);

  router_k<<<T_TOK, 64, 0, stream>>>(x, gate_w, out_logits, sel, selw);
  scan_k<<<1, 1024, 0, stream>>>(sel, pos, offs, rowtok, pairrow);
  gather_k<<<NRP, 256, 0, stream>>>(x, rowtok, xg);
  xa_k<<<NRP / 2, 64, 0, stream>>>(xg, abgu, offs, xagu);
  gemm1_k<<<dim3(32, MTILES), 256, 0, stream>>>(xg, wgu_t, gate_up_b, B_gate, B_up,
                                                xagu, offs, actb);
  aad_k<<<NRP / 2, 64, 0, stream>>>(actb, adb, offs, aadb);
  gemm2_k<<<dim3(8, MTILES, 2), 256, 0, stream>>>(actb, wd_t, down_b, B_down, aadb, offs, downb);
  combine_k<<<T_TOK, 256, 0, stream>>>(downb, pairrow, selw, out_final);
}

// Round 6
// 259.985 us; speedup vs baseline: 1.4369x; 1.0479x over previous
//
#include <hip/hip_runtime.h>

#define T_TOK 4096
#define DIM   1024
#define FFD   2048
#define NEXP  4
#define NRP   8704      // 68*128 padded row capacity
#define MTILES 68

typedef unsigned short u16;
typedef __attribute__((ext_vector_type(8))) short short8;
typedef __attribute__((ext_vector_type(4))) float f32x4;
typedef __attribute__((ext_vector_type(8))) unsigned short u16x8;
typedef __attribute__((ext_vector_type(4))) unsigned short u16x4;

typedef __attribute__((address_space(1))) unsigned int as1_u32;
typedef __attribute__((address_space(3))) unsigned int as3_u32;

__device__ __forceinline__ u16 f2bf(float f) {
  union { float f; unsigned u; } v; v.f = f;
  unsigned u = v.u;
  return (u16)((u + 0x7fffu + ((u >> 16) & 1u)) >> 16);   // RNE
}
__device__ __forceinline__ float bf2f(u16 h) {
  union { unsigned u; float f; } v; v.u = ((unsigned)h) << 16;
  return v.f;
}
__device__ __forceinline__ void gload16(const void* g, void* l) {
  __builtin_amdgcn_global_load_lds((const as1_u32*)g, (as3_u32*)l, 16, 0, 0);
}

// ---------------- router: fp32 logits, softmax top-2, renorm ----------------
__global__ void router_k(const float* __restrict__ x, const float* __restrict__ gw,
                         float* __restrict__ logits_out, int* __restrict__ sel,
                         float* __restrict__ selw) {
  int t = blockIdx.x;
  int lane = threadIdx.x;           // block = 64 (one wave)
  float xv[16];
#pragma unroll
  for (int i = 0; i < 16; ++i) xv[i] = x[(size_t)t * DIM + lane + i * 64];
  float l[4];
#pragma unroll
  for (int e = 0; e < 4; ++e) {
    float s = 0.f;
#pragma unroll
    for (int i = 0; i < 16; ++i) s += xv[i] * gw[e * DIM + lane + i * 64];
#pragma unroll
    for (int off = 32; off > 0; off >>= 1) s += __shfl_xor(s, off, 64);
    l[e] = s;
  }
  if (lane == 0) {
#pragma unroll
    for (int e = 0; e < 4; ++e) logits_out[(size_t)t * 4 + e] = l[e];
    int e0 = 0; float b0 = l[0];
    for (int e = 1; e < 4; ++e) if (l[e] > b0) { b0 = l[e]; e0 = e; }
    int e1 = -1; float b1 = -3.4e38f;
    for (int e = 0; e < 4; ++e) if (e != e0 && l[e] > b1) { b1 = l[e]; e1 = e; }
    float p1 = expf(b1 - b0);
    float w0 = 1.f / (1.f + p1);
    sel[2 * t] = e0; sel[2 * t + 1] = e1;
    selw[2 * t] = w0; selw[2 * t + 1] = 1.f - w0;
  }
}

// ------------- deterministic bucket assignment (single block) ---------------
__global__ void scan_k(const int* __restrict__ sel, int* __restrict__ pos,
                       int* __restrict__ offs, int* __restrict__ rowtok,
                       int* __restrict__ pairrow) {
  __shared__ int base[4];
  __shared__ int wsum[16][4];
  __shared__ int off_s[5];
  int tid = threadIdx.x, lane = tid & 63, wid = tid >> 6;   // 1024 threads = 16 waves
  if (tid < 4) base[tid] = 0;
  __syncthreads();
  for (int chunk = 0; chunk < 4; ++chunk) {
    int t = chunk * 1024 + tid;
    int e0 = sel[2 * t], e1 = sel[2 * t + 1];
    unsigned long long ltm = (1ull << lane) - 1ull;
    bool f[4]; int within[4];
#pragma unroll
    for (int e = 0; e < 4; ++e) {
      f[e] = (e0 == e) || (e1 == e);
      unsigned long long m = __ballot(f[e]);
      within[e] = __popcll(m & ltm);
      if (lane == 0) wsum[wid][e] = __popcll(m);
    }
    __syncthreads();
    int wbase[4] = {0, 0, 0, 0}, tot[4] = {0, 0, 0, 0};
    for (int i = 0; i < 16; ++i)
#pragma unroll
      for (int e = 0; e < 4; ++e) {
        int v = wsum[i][e];
        if (i < wid) wbase[e] += v;
        tot[e] += v;
      }
#pragma unroll
    for (int e = 0; e < 4; ++e)
      if (f[e]) {
        int p = base[e] + wbase[e] + within[e];
        if (e0 == e) pos[2 * t] = p; else pos[2 * t + 1] = p;
      }
    __syncthreads();
    if (tid < 4) base[tid] += tot[tid];
    __syncthreads();
  }
  if (tid == 0) {
    int o = 0;
    for (int e = 0; e < 4; ++e) { off_s[e] = o; o += ((base[e] + 127) >> 7) << 7; }
    off_s[4] = o;
    for (int i = 0; i < 5; ++i) offs[i] = off_s[i];
  }
  __syncthreads();
  for (int r = tid; r < NRP; r += 1024) rowtok[r] = -1;
  __syncthreads();
  for (int t = tid; t < T_TOK; t += 1024) {
#pragma unroll
    for (int s = 0; s < 2; ++s) {
      int e = sel[2 * t + s];
      int rr = off_s[e] + pos[2 * t + s];
      pairrow[2 * t + s] = rr;
      rowtok[rr] = t;
    }
  }
}

// ---------------- gather x rows (bucket order) -> bf16 ----------------------
__global__ void gather_k(const float* __restrict__ x, const int* __restrict__ rowtok,
                         u16* __restrict__ xg) {
  int r = blockIdx.x, tid = threadIdx.x;   // 256 threads, 4 floats each
  int t = rowtok[r];
  float4 v = make_float4(0.f, 0.f, 0.f, 0.f);
  if (t >= 0) v = ((const float4*)(x + (size_t)t * DIM))[tid];
  u16x4 o;
  o[0] = f2bf(v.x); o[1] = f2bf(v.y); o[2] = f2bf(v.z); o[3] = f2bf(v.w);
  ((u16x4*)(xg + (size_t)r * DIM))[tid] = o;
}

// -------- pre-convert LoRA A matrices to bf16 (abgu[4][32][1024], adb[4][16][2048])
__global__ void cvtA_k(const float* __restrict__ Ag, const float* __restrict__ Au,
                       const float* __restrict__ Ad, u16* __restrict__ abgu,
                       u16* __restrict__ adb) {
  int g = blockIdx.x * 256 + threadIdx.x;   // each handles 4 elements
  if (g < 32768) {
    int flat = g * 4;
    int e = flat >> 15;
    int rem = flat & 32767;
    int q = rem >> 10;
    int d = rem & 1023;
    const float* src = (q < 16) ? (Ag + ((size_t)e * 16 + q) * DIM + d)
                                : (Au + ((size_t)e * 16 + (q - 16)) * DIM + d);
    float4 v = *(const float4*)src;
    u16x4 o; o[0] = f2bf(v.x); o[1] = f2bf(v.y); o[2] = f2bf(v.z); o[3] = f2bf(v.w);
    *(u16x4*)(abgu + (size_t)flat) = o;
  } else {
    int flat = (g - 32768) * 4;
    float4 v = *(const float4*)(Ad + flat);
    u16x4 o; o[0] = f2bf(v.x); o[1] = f2bf(v.y); o[2] = f2bf(v.z); o[3] = f2bf(v.w);
    *(u16x4*)(adb + (size_t)flat) = o;
  }
}

// ---------------- per-row LoRA A-projections, 2 rows per wave ----------------
__global__ void xa_k(const u16* __restrict__ xg, const u16* __restrict__ abgu,
                     const int* __restrict__ offs, float* __restrict__ xagu) {
  int r0 = blockIdx.x * 2, lane = threadIdx.x;   // block = 64
  int e = 0;
  if (r0 >= offs[1]) e = 1;
  if (r0 >= offs[2]) e = 2;
  if (r0 >= offs[3]) e = 3;
  float x0[16], x1[16];
#pragma unroll
  for (int i = 0; i < 4; ++i) {
    u16x4 v0 = ((const u16x4*)(xg + (size_t)r0 * DIM))[lane + i * 64];
    u16x4 v1 = ((const u16x4*)(xg + (size_t)(r0 + 1) * DIM))[lane + i * 64];
#pragma unroll
    for (int j = 0; j < 4; ++j) { x0[i * 4 + j] = bf2f(v0[j]); x1[i * 4 + j] = bf2f(v1[j]); }
  }
  const u16* A = abgu + (size_t)e * 32 * DIM;
  for (int q = 0; q < 32; ++q) {
    float s0 = 0.f, s1 = 0.f;
#pragma unroll
    for (int i = 0; i < 4; ++i) {
      u16x4 av = ((const u16x4*)(A + (size_t)q * DIM))[lane + i * 64];
#pragma unroll
      for (int j = 0; j < 4; ++j) {
        float a = bf2f(av[j]);
        s0 += x0[i * 4 + j] * a; s1 += x1[i * 4 + j] * a;
      }
    }
#pragma unroll
    for (int off = 32; off > 0; off >>= 1) { s0 += __shfl_xor(s0, off, 64); s1 += __shfl_xor(s1, off, 64); }
    if (lane == 0) { xagu[(size_t)r0 * 32 + q] = s0; xagu[(size_t)(r0 + 1) * 32 + q] = s1; }
  }
}

__global__ void aad_k(const u16* __restrict__ act, const u16* __restrict__ adb,
                      const int* __restrict__ offs, float* __restrict__ aad) {
  int r0 = blockIdx.x * 2, lane = threadIdx.x;
  int e = 0;
  if (r0 >= offs[1]) e = 1;
  if (r0 >= offs[2]) e = 2;
  if (r0 >= offs[3]) e = 3;
  float x0[32], x1[32];
#pragma unroll
  for (int i = 0; i < 8; ++i) {
    u16x4 v0 = ((const u16x4*)(act + (size_t)r0 * FFD))[lane + i * 64];
    u16x4 v1 = ((const u16x4*)(act + (size_t)(r0 + 1) * FFD))[lane + i * 64];
#pragma unroll
    for (int j = 0; j < 4; ++j) { x0[i * 4 + j] = bf2f(v0[j]); x1[i * 4 + j] = bf2f(v1[j]); }
  }
  const u16* A = adb + (size_t)e * 16 * FFD;
  for (int q = 0; q < 16; ++q) {
    float s0 = 0.f, s1 = 0.f;
#pragma unroll
    for (int i = 0; i < 8; ++i) {
      u16x4 av = ((const u16x4*)(A + (size_t)q * FFD))[lane + i * 64];
#pragma unroll
      for (int j = 0; j < 4; ++j) {
        float a = bf2f(av[j]);
        s0 += x0[i * 4 + j] * a; s1 += x1[i * 4 + j] * a;
      }
    }
#pragma unroll
    for (int off = 32; off > 0; off >>= 1) { s0 += __shfl_xor(s0, off, 64); s1 += __shfl_xor(s1, off, 64); }
    if (lane == 0) { aad[(size_t)r0 * 16 + q] = s0; aad[(size_t)(r0 + 1) * 16 + q] = s1; }
  }
}

// ---------------- weight transpose fp32[K][N] -> bf16[N][K] ------------------
__global__ void transpose_k(const float* __restrict__ in, u16* __restrict__ out,
                            int K, int N) {
  int e = blockIdx.z;
  int n0 = blockIdx.x * 32, k0 = blockIdx.y * 32;
  const float* I = in + (size_t)e * K * N;
  u16* O = out + (size_t)e * N * K;
  __shared__ u16 tile[32][33];
#pragma unroll
  for (int i = 0; i < 4; ++i) {
    int k = k0 + threadIdx.y + i * 8;
    tile[threadIdx.y + i * 8][threadIdx.x] = f2bf(I[(size_t)k * N + n0 + threadIdx.x]);
  }
  __syncthreads();
#pragma unroll
  for (int i = 0; i < 4; ++i) {
    int n = n0 + threadIdx.y + i * 8;
    O[(size_t)n * K + k0 + threadIdx.x] = tile[threadIdx.x][threadIdx.y + i * 8];
  }
}

// ---------------- GEMM1: act = swiglu(x@Wgu + b + lora) ---------------------
// Block tile: 128 rows x 256 B-rows (= 128 f-cols: gate rows 0-127, up 128-255).
// 4 waves 2x2 (wm=rows-half, wn=B-half), each wave 64x128 via 4 A x 8 B frags
// -> 43.7 FLOP per LDS byte (LDS-BW no longer binding). Triple-buffered 24KB
// staging, counted vmcnt(6) depth-2 pipeline, full unroll. T2 swizzle.
__global__ __launch_bounds__(256, 2) void gemm1_k(
    const u16* __restrict__ xg, const u16* __restrict__ wgu_t,
    const float* __restrict__ gub, const float* __restrict__ Bg,
    const float* __restrict__ Bu, const float* __restrict__ xagu,
    const int* __restrict__ offs, u16* __restrict__ act) {
  __shared__ __align__(16) u16 sAB[36864];   // 3 bufs x (A[128][32] + B[256][32]) = 72KB
  int tid = threadIdx.x, w = tid >> 6, lane = tid & 63;
  int f0 = blockIdx.x * 128;
  int row0 = blockIdx.y * 128;
  int e = 0;
  if (row0 >= offs[1]) e = 1;
  if (row0 >= offs[2]) e = 2;
  if (row0 >= offs[3]) e = 3;
  int wm = w >> 1, wn = w & 1;

  int srow = lane >> 2;
  int scol = ((lane & 3) ^ ((lane >> 3) & 3)) * 8;     // pre-swizzled global src (T2)
  const u16* gA = xg + (size_t)(row0 + w * 32 + srow) * DIM + scol;
  int bhalf = (w < 2) ? (f0 + w * 64) : (2048 + f0 + (w - 2) * 64);
  const u16* gB = wgu_t + ((size_t)e << 22) + (size_t)(bhalf + srow) * DIM + scol;
  int fo = (((lane >> 4) ^ ((lane >> 1) & 3))) * 8;    // swizzled fragment k-offset
  int arb = (wm * 64 + (lane & 15)) * 32 + fo;         // A-frag base (rel. to buf)
  int brb = 4096 + (wn * 128 + (lane & 15)) * 32 + fo; // B-frag base (rel. to buf)

  f32x4 acc[4][8];
#pragma unroll
  for (int i = 0; i < 4; ++i)
#pragma unroll
    for (int j = 0; j < 8; ++j) acc[i][j] = f32x4{0.f, 0.f, 0.f, 0.f};

  // prologue: batches 0,1 -> bufs 0,1 (6 gloads per wave per batch)
#pragma unroll
  for (int p = 0; p < 2; ++p) {
    u16* dA = sAB + p * 12288 + w * 1024;
    gload16(gA + p * 32, dA); gload16(gA + 16 * DIM + p * 32, dA + 512);
    u16* dB = sAB + p * 12288 + 4096 + w * 2048;
    gload16(gB + p * 32, dB); gload16(gB + 16 * DIM + p * 32, dB + 512);
    gload16(gB + 32 * DIM + p * 32, dB + 1024); gload16(gB + 48 * DIM + p * 32, dB + 1536);
  }
#pragma unroll
  for (int t = 0; t < 32; ++t) {
    if (t == 31) asm volatile("s_waitcnt vmcnt(0)\n\ts_barrier" ::: "memory");
    else         asm volatile("s_waitcnt vmcnt(6)\n\ts_barrier" ::: "memory");
    if (t < 30) {
      int kk = (t + 2) * 32;
      int bo = ((t + 2) % 3) * 12288;
      u16* dA = sAB + bo + w * 1024;
      gload16(gA + kk, dA); gload16(gA + 16 * DIM + kk, dA + 512);
      u16* dB = sAB + bo + 4096 + w * 2048;
      gload16(gB + kk, dB); gload16(gB + 16 * DIM + kk, dB + 512);
      gload16(gB + 32 * DIM + kk, dB + 1024); gload16(gB + 48 * DIM + kk, dB + 1536);
    }
    const u16* cb = sAB + (t % 3) * 12288;
    short8 a[4], bb[8];
#pragma unroll
    for (int mi = 0; mi < 4; ++mi)
      a[mi] = *(const short8*)&cb[arb + mi * 512];
#pragma unroll
    for (int ni = 0; ni < 8; ++ni)
      bb[ni] = *(const short8*)&cb[brb + ni * 512];
#pragma unroll
    for (int mi = 0; mi < 4; ++mi)
#pragma unroll
      for (int ni = 0; ni < 8; ++ni)
        acc[mi][ni] = __builtin_amdgcn_mfma_f32_16x16x32_bf16(a[mi], bb[ni], acc[mi][ni], 0, 0, 0);
  }

  // ---- LoRA + bias as one extra K=32 MFMA step ----
  // A-lora: buf0.A = [2*xag | 1@k16] (for wn=0), buf1.A = [2*xau | 1@k16] (wn=1)
  // B-lora: buf0.B rows 0-127 = B_gate+bias, rows 128-255 = B_up+bias
  __syncthreads();
  {
    int rl = tid & 127, half = tid >> 7;
    int sw = (rl >> 1) & 3;
    int abase = half * 12288 + rl * 32;
    u16 tmp[16];
#pragma unroll
    for (int q = 0; q < 16; ++q) tmp[q] = f2bf(2.f * xagu[(size_t)(row0 + rl) * 32 + half * 16 + q]);
    *(u16x8*)&sAB[abase + (0 ^ sw) * 8] = *(u16x8*)&tmp[0];
    *(u16x8*)&sAB[abase + (1 ^ sw) * 8] = *(u16x8*)&tmp[8];
    u16 t2[8] = {0x3f80, 0, 0, 0, 0, 0, 0, 0};
    u16 t3[8] = {0, 0, 0, 0, 0, 0, 0, 0};
    *(u16x8*)&sAB[abase + (2 ^ sw) * 8] = *(u16x8*)&t2[0];
    *(u16x8*)&sAB[abase + (3 ^ sw) * 8] = *(u16x8*)&t3[0];
    // B-lora: one row per thread
    int r = tid, fb = r & 127, bh = r >> 7;
    int swb = (r >> 1) & 3;
    int bbase = 4096 + r * 32;
    const float* Bsrc = bh ? Bu : Bg;
    float bias = gub[e * 4096 + (bh ? (2048 + f0 + fb) : (f0 + fb))];
    u16 tb[16];
#pragma unroll
    for (int q = 0; q < 16; ++q) tb[q] = f2bf(Bsrc[((size_t)e * FFD + f0 + fb) * 16 + q]);
    *(u16x8*)&sAB[bbase + (0 ^ swb) * 8] = *(u16x8*)&tb[0];
    *(u16x8*)&sAB[bbase + (1 ^ swb) * 8] = *(u16x8*)&tb[8];
    u16 t2b[8] = {f2bf(bias), 0, 0, 0, 0, 0, 0, 0};
    *(u16x8*)&sAB[bbase + (2 ^ swb) * 8] = *(u16x8*)&t2b[0];
    *(u16x8*)&sAB[bbase + (3 ^ swb) * 8] = *(u16x8*)&t3[0];
  }
  __syncthreads();
  {
    int aBase = wn ? 12288 : 0;
    short8 a[4], bb[8];
#pragma unroll
    for (int mi = 0; mi < 4; ++mi)
      a[mi] = *(const short8*)&sAB[aBase + arb + mi * 512];
#pragma unroll
    for (int ni = 0; ni < 8; ++ni)
      bb[ni] = *(const short8*)&sAB[brb + ni * 512];
#pragma unroll
    for (int mi = 0; mi < 4; ++mi)
#pragma unroll
      for (int ni = 0; ni < 8; ++ni)
        acc[mi][ni] = __builtin_amdgcn_mfma_f32_16x16x32_bf16(a[mi], bb[ni], acc[mi][ni], 0, 0, 0);
  }
  // ---- SwiGLU via LDS exchange: sOut[128][256] bf16, XOR bank-swizzled ----
  __syncthreads();
#pragma unroll
  for (int mi = 0; mi < 4; ++mi)
#pragma unroll
    for (int ni = 0; ni < 8; ++ni)
#pragma unroll
      for (int j = 0; j < 4; ++j) {
        int row = wm * 64 + mi * 16 + (lane >> 4) * 4 + j;
        int br = wn * 128 + ni * 16 + (lane & 15);
        int key = ((row & 3) ^ ((row >> 2) & 3)) << 4;
        sAB[row * 256 + (br ^ key)] = f2bf(acc[mi][ni][j]);
      }
  __syncthreads();
  {
    int fc = (tid & 15) * 8;
    int rb = tid >> 4;
#pragma unroll
    for (int it = 0; it < 8; ++it) {
      int row = rb + it * 16;
      int key = ((row & 3) ^ ((row >> 2) & 3)) << 4;
      u16x8 gv = *(const u16x8*)&sAB[row * 256 + (fc ^ key)];
      u16x8 uv = *(const u16x8*)&sAB[row * 256 + 128 + (fc ^ key)];
      u16x8 ov;
#pragma unroll
      for (int j = 0; j < 8; ++j) {
        float g = bf2f(gv[j]);
        float u = bf2f(uv[j]);
        float s = g / (1.f + __expf(-g));
        ov[j] = f2bf(s * u);
      }
      *(u16x8*)(act + (size_t)(row0 + row) * FFD + f0 + fc) = ov;
    }
  }
}

// ------- GEMM2: down = act@Wd + b + lora; 128x256 tile, split-K=2 -----------
__global__ __launch_bounds__(256, 2) void gemm2_k(
    const u16* __restrict__ act, const u16* __restrict__ wd_t,
    const float* __restrict__ db, const float* __restrict__ Bd,
    const float* __restrict__ aad, const int* __restrict__ offs,
    u16* __restrict__ down) {
  __shared__ __align__(16) u16 sAB[36864];
  int tid = threadIdx.x, w = tid >> 6, lane = tid & 63;
  int n0 = blockIdx.x * 256;
  int row0 = blockIdx.y * 128;
  int ks = blockIdx.z;
  size_t kbase = (size_t)ks * 1024;
  int e = 0;
  if (row0 >= offs[1]) e = 1;
  if (row0 >= offs[2]) e = 2;
  if (row0 >= offs[3]) e = 3;
  int wm = w >> 1, wn = w & 1;

  int srow = lane >> 2;
  int scol = ((lane & 3) ^ ((lane >> 3) & 3)) * 8;
  const u16* gA = act + (size_t)(row0 + w * 32 + srow) * FFD + kbase + scol;
  const u16* gB = wd_t + (size_t)e * DIM * FFD + (size_t)(n0 + w * 64 + srow) * FFD + kbase + scol;
  int fo = (((lane >> 4) ^ ((lane >> 1) & 3))) * 8;
  int arb = (wm * 64 + (lane & 15)) * 32 + fo;
  int brb = 4096 + (wn * 128 + (lane & 15)) * 32 + fo;

  f32x4 acc[4][8];
#pragma unroll
  for (int i = 0; i < 4; ++i)
#pragma unroll
    for (int j = 0; j < 8; ++j) acc[i][j] = f32x4{0.f, 0.f, 0.f, 0.f};

#pragma unroll
  for (int p = 0; p < 2; ++p) {
    u16* dA = sAB + p * 12288 + w * 1024;
    gload16(gA + p * 32, dA); gload16(gA + 16 * FFD + p * 32, dA + 512);
    u16* dB = sAB + p * 12288 + 4096 + w * 2048;
    gload16(gB + p * 32, dB); gload16(gB + 16 * FFD + p * 32, dB + 512);
    gload16(gB + 32 * FFD + p * 32, dB + 1024); gload16(gB + 48 * FFD + p * 32, dB + 1536);
  }
#pragma unroll
  for (int t = 0; t < 32; ++t) {
    if (t == 31) asm volatile("s_waitcnt vmcnt(0)\n\ts_barrier" ::: "memory");
    else         asm volatile("s_waitcnt vmcnt(6)\n\ts_barrier" ::: "memory");
    if (t < 30) {
      int kk = (t + 2) * 32;
      int bo = ((t + 2) % 3) * 12288;
      u16* dA = sAB + bo + w * 1024;
      gload16(gA + kk, dA); gload16(gA + 16 * FFD + kk, dA + 512);
      u16* dB = sAB + bo + 4096 + w * 2048;
      gload16(gB + kk, dB); gload16(gB + 16 * FFD + kk, dB + 512);
      gload16(gB + 32 * FFD + kk, dB + 1024); gload16(gB + 48 * FFD + kk, dB + 1536);
    }
    const u16* cb = sAB + (t % 3) * 12288;
    short8 a[4], bb[8];
#pragma unroll
    for (int mi = 0; mi < 4; ++mi)
      a[mi] = *(const short8*)&cb[arb + mi * 512];
#pragma unroll
    for (int ni = 0; ni < 8; ++ni)
      bb[ni] = *(const short8*)&cb[brb + ni * 512];
#pragma unroll
    for (int mi = 0; mi < 4; ++mi)
#pragma unroll
      for (int ni = 0; ni < 8; ++ni)
        acc[mi][ni] = __builtin_amdgcn_mfma_f32_16x16x32_bf16(a[mi], bb[ni], acc[mi][ni], 0, 0, 0);
  }

  if (ks == 0) {
    // ---- LoRA-down + bias as one extra K=32 MFMA step ----
    __syncthreads();
    {
      int r = tid >> 1, kh = tid & 1;
      int sw = (r >> 1) & 3;
      int o0 = r * 32 + ((2 * kh + 0) ^ sw) * 8;
      int o1 = r * 32 + ((2 * kh + 1) ^ sw) * 8;
      u16 tmp[16];
      if (kh == 0) {
#pragma unroll
        for (int q = 0; q < 16; ++q) tmp[q] = f2bf(2.f * aad[(size_t)(row0 + r) * 16 + q]);
      } else {
#pragma unroll
        for (int q = 0; q < 16; ++q) tmp[q] = 0;
        tmp[0] = 0x3f80;
      }
      *(u16x8*)&sAB[o0] = *(u16x8*)&tmp[0];
      *(u16x8*)&sAB[o1] = *(u16x8*)&tmp[8];
      // B-lora: one row per thread (256 rows)
      int r2 = tid;
      int swb = (r2 >> 1) & 3;
      int bbase = 4096 + r2 * 32;
      u16 tb[16];
#pragma unroll
      for (int q = 0; q < 16; ++q) tb[q] = f2bf(Bd[((size_t)e * DIM + n0 + r2) * 16 + q]);
      *(u16x8*)&sAB[bbase + (0 ^ swb) * 8] = *(u16x8*)&tb[0];
      *(u16x8*)&sAB[bbase + (1 ^ swb) * 8] = *(u16x8*)&tb[8];
      u16 t2b[8] = {f2bf(db[e * DIM + n0 + r2]), 0, 0, 0, 0, 0, 0, 0};
      u16 t3b[8] = {0, 0, 0, 0, 0, 0, 0, 0};
      *(u16x8*)&sAB[bbase + (2 ^ swb) * 8] = *(u16x8*)&t2b[0];
      *(u16x8*)&sAB[bbase + (3 ^ swb) * 8] = *(u16x8*)&t3b[0];
    }
    __syncthreads();
    {
      short8 a[4], bb[8];
#pragma unroll
      for (int mi = 0; mi < 4; ++mi)
        a[mi] = *(const short8*)&sAB[arb + mi * 512];
#pragma unroll
      for (int ni = 0; ni < 8; ++ni)
        bb[ni] = *(const short8*)&sAB[brb + ni * 512];
#pragma unroll
      for (int mi = 0; mi < 4; ++mi)
#pragma unroll
        for (int ni = 0; ni < 8; ++ni)
          acc[mi][ni] = __builtin_amdgcn_mfma_f32_16x16x32_bf16(a[mi], bb[ni], acc[mi][ni], 0, 0, 0);
    }
  }
  // ---- store bf16 partial ----
#pragma unroll
  for (int mi = 0; mi < 4; ++mi)
#pragma unroll
    for (int ni = 0; ni < 8; ++ni)
#pragma unroll
      for (int j = 0; j < 4; ++j) {
        int lr = wm * 64 + mi * 16 + (lane >> 4) * 4 + j;
        int lc = wn * 128 + ni * 16 + (lane & 15);
        down[((size_t)ks * NRP + row0 + lr) * DIM + n0 + lc] = f2bf(acc[mi][ni][j]);
      }
}

// ---------------- weighted combine (sums split-K halves) --------------------
__global__ void combine_k(const u16* __restrict__ down, const int* __restrict__ pairrow,
                          const float* __restrict__ selw, float* __restrict__ out) {
  int t = blockIdx.x, tid = threadIdx.x;   // 256 threads, 4 cols each
  int r0 = pairrow[2 * t], r1 = pairrow[2 * t + 1];
  float w0 = selw[2 * t], w1 = selw[2 * t + 1];
  u16x4 a0 = *(const u16x4*)(down + ((size_t)r0) * DIM + tid * 4);
  u16x4 a1 = *(const u16x4*)(down + ((size_t)NRP + r0) * DIM + tid * 4);
  u16x4 b0 = *(const u16x4*)(down + ((size_t)r1) * DIM + tid * 4);
  u16x4 b1 = *(const u16x4*)(down + ((size_t)NRP + r1) * DIM + tid * 4);
  f32x4 o;
#pragma unroll
  for (int j = 0; j < 4; ++j)
    o[j] = w0 * (bf2f(a0[j]) + bf2f(a1[j])) + w1 * (bf2f(b0[j]) + bf2f(b1[j]));
  *(f32x4*)(out + (size_t)t * DIM + tid * 4) = o;
}

extern "C" void kernel_launch(void* const* d_in, const int* in_sizes, int n_in,
                              void* d_out, int out_size, void* d_ws, size_t ws_size,
                              hipStream_t stream) {
  const float* x         = (const float*)d_in[0];
  const float* gate_w    = (const float*)d_in[1];
  const float* gate_up_w = (const float*)d_in[2];
  const float* gate_up_b = (const float*)d_in[3];
  const float* down_w    = (const float*)d_in[4];
  const float* down_b    = (const float*)d_in[5];
  const float* A_gate    = (const float*)d_in[6];
  const float* B_gate    = (const float*)d_in[7];
  const float* A_up      = (const float*)d_in[8];
  const float* B_up      = (const float*)d_in[9];
  const float* A_down    = (const float*)d_in[10];
  const float* B_down    = (const float*)d_in[11];

  float* out_final  = (float*)d_out;
  float* out_logits = out_final + (size_t)T_TOK * DIM;

  char* ws = (char*)d_ws;
  size_t o = 0;
  auto take = [&](size_t bytes) -> void* {
    void* p = ws + o;
    o = (o + bytes + 255) & ~(size_t)255;
    return p;
  };
  int*   offs    = (int*)take(64);
  int*   sel     = (int*)take((size_t)T_TOK * 2 * 4);
  float* selw    = (float*)take((size_t)T_TOK * 2 * 4);
  int*   pos     = (int*)take((size_t)T_TOK * 2 * 4);
  int*   pairrow = (int*)take((size_t)T_TOK * 2 * 4);
  int*   rowtok  = (int*)take((size_t)NRP * 4);
  float* xagu    = (float*)take((size_t)NRP * 32 * 4);
  float* aadb    = (float*)take((size_t)NRP * 16 * 4);
  u16*   abgu    = (u16*)take((size_t)NEXP * 32 * DIM * 2);
  u16*   adb     = (u16*)take((size_t)NEXP * 16 * FFD * 2);
  u16*   xg      = (u16*)take((size_t)NRP * DIM * 2);
  u16*   actb    = (u16*)take((size_t)NRP * FFD * 2);
  u16*   downb   = (u16*)take((size_t)2 * NRP * DIM * 2);
  u16*   wgu_t   = (u16*)take((size_t)NEXP * 2 * FFD * DIM * 2);
  u16*   wd_t    = (u16*)take((size_t)NEXP * DIM * FFD * 2);
  (void)ws_size; (void)in_sizes; (void)n_in; (void)out_size;

  // weight transposes (fp32 [K][N] -> bf16 [N][K]) — independent of routing
  transpose_k<<<dim3(128, 32, NEXP), dim3(32, 8), 0, stream>>>(gate_up_w, wgu_t, DIM, 2 * FFD);
  transpose_k<<<dim3(32, 64, NEXP), dim3(32, 8), 0, stream>>>(down_w, wd_t, FFD, DIM);
  cvtA_k<<<256, 256, 0, stream>>>(A_gate, A_up, A_down, abgu, adb);

  router_k<<<T_TOK, 64, 0, stream>>>(x, gate_w, out_logits, sel, selw);
  scan_k<<<1, 1024, 0, stream>>>(sel, pos, offs, rowtok, pairrow);
  gather_k<<<NRP, 256, 0, stream>>>(x, rowtok, xg);
  xa_k<<<NRP / 2, 64, 0, stream>>>(xg, abgu, offs, xagu);
  gemm1_k<<<dim3(16, MTILES), 256, 0, stream>>>(xg, wgu_t, gate_up_b, B_gate, B_up,
                                                xagu, offs, actb);
  aad_k<<<NRP / 2, 64, 0, stream>>>(actb, adb, offs, aadb);
  gemm2_k<<<dim3(4, MTILES, 2), 256, 0, stream>>>(actb, wd_t, down_b, B_down, aadb, offs, downb);
  combine_k<<<T_TOK, 256, 0, stream>>>(downb, pairrow, selw, out_final);
}